// Round 1
// baseline (2665.947 us; speedup 1.0000x reference)
//
#include <hip/hip_runtime.h>

#define NN 100000
#define NE 3200000
#define NG 2000
static constexpr float BN_EPS = 1e-5f;

// ---------------- degree / norm ----------------
__global__ __launch_bounds__(256) void k_init_deg(float* deg) {
    int i = blockIdx.x * 256 + threadIdx.x;
    if (i < NN) deg[i] = 1.0f;   // self-loop
}

__global__ __launch_bounds__(256) void k_count_deg(const int* __restrict__ dst, float* deg) {
    int e = blockIdx.x * 256 + threadIdx.x;
    if (e < NE) atomicAdd(&deg[dst[e]], 1.0f);
}

__global__ __launch_bounds__(256) void k_make_dinv(const float* __restrict__ deg, float* __restrict__ dinv) {
    int i = blockIdx.x * 256 + threadIdx.x;
    if (i < NN) dinv[i] = rsqrtf(fmaxf(deg[i], 1.0f));
}

// ---------------- h1 = x @ W1   (N x 10) @ (10 x 64) ----------------
__global__ __launch_bounds__(256) void k_mm1(const float* __restrict__ x, const float* __restrict__ W,
                                             float* __restrict__ h) {
    int row = blockIdx.x * 4 + (threadIdx.x >> 6);
    int f   = threadIdx.x & 63;
    if (row >= NN) return;
    float acc = 0.f;
#pragma unroll
    for (int k = 0; k < 10; ++k) acc += x[row * 10 + k] * W[k * 64 + f];
    h[row * 64 + f] = acc;
}

// ---------------- agg init: self-loop + bias ----------------
template <int F>
__global__ __launch_bounds__(256) void k_self_init(const float* __restrict__ h, const float* __restrict__ dinv,
                                                   const float* __restrict__ b, float* __restrict__ agg) {
    int idx = blockIdx.x * 256 + threadIdx.x;
    if (idx >= NN * F) return;
    int i = idx >> (F == 64 ? 6 : 7);
    int f = idx & (F - 1);
    float di = dinv[i];
    agg[idx] = h[idx] * di * di + b[f];
}

// ---------------- edge scatter ----------------
template <int F, int LOGF>
__global__ __launch_bounds__(256) void k_edge_scatter(const float* __restrict__ h, const int* __restrict__ src,
                                                      const int* __restrict__ dst, const float* __restrict__ dinv,
                                                      float* __restrict__ agg) {
    int idx = blockIdx.x * 256 + threadIdx.x;
    if (idx >= NE * F) return;          // NE*F <= 409.6M < 2^31
    int e = idx >> LOGF;
    int f = idx & (F - 1);
    int s = src[e];
    int d = dst[e];
    float w = dinv[s] * dinv[d];
    atomicAdd(&agg[d * F + f], h[s * F + f] * w);
}

// ---------------- batchnorm ----------------
__global__ __launch_bounds__(256) void k_zero_sums(float* sums) {
    if (threadIdx.x < 256 && blockIdx.x == 0) sums[threadIdx.x] = 0.f;
}

template <int F>
__global__ __launch_bounds__(256) void k_bn_stats(const float* __restrict__ agg, float* __restrict__ sums) {
    __shared__ float ls[256];
    __shared__ float lq[256];
    int t = threadIdx.x;
    int T = gridDim.x * 256;            // multiple of F
    float s = 0.f, q = 0.f;
    for (int idx = blockIdx.x * 256 + t; idx < NN * F; idx += T) {
        float v = agg[idx];
        s += v;
        q += v * v;
    }
    ls[t] = s;
    lq[t] = q;
    __syncthreads();
    if (t < F) {
        float S = 0.f, Q = 0.f;
#pragma unroll
        for (int j = t; j < 256; j += F) { S += ls[j]; Q += lq[j]; }
        atomicAdd(&sums[t], S);
        atomicAdd(&sums[F + t], Q);
    }
}

template <int F>
__global__ __launch_bounds__(256) void k_bn_apply_relu(float* __restrict__ agg, const float* __restrict__ sums,
                                                       const float* __restrict__ g, const float* __restrict__ be) {
    int idx = blockIdx.x * 256 + threadIdx.x;
    if (idx >= NN * F) return;
    int f = idx & (F - 1);
    const float invn = 1.0f / (float)NN;
    float mu  = sums[f] * invn;
    float var = sums[F + f] * invn - mu * mu;
    float sc  = g[f] * rsqrtf(var + BN_EPS);
    float v   = (agg[idx] - mu) * sc + be[f];
    agg[idx]  = fmaxf(v, 0.f);
}

// ---------------- h2 = h1r @ W2   (N x 64) @ (64 x 128) ----------------
__global__ __launch_bounds__(256) void k_mm2(const float* __restrict__ hin, const float* __restrict__ W,
                                             float* __restrict__ hout) {
    __shared__ float row[2][64];
    int r = threadIdx.x >> 7;           // wave-uniform
    int f = threadIdx.x & 127;
    int i = blockIdx.x * 2 + r;
    if (f < 64 && i < NN) row[r][f] = hin[i * 64 + f];
    __syncthreads();
    if (i >= NN) return;
    float acc = 0.f;
#pragma unroll
    for (int k = 0; k < 64; ++k) acc += row[r][k] * W[k * 128 + f];
    hout[i * 128 + f] = acc;
}

// ---------------- pooling ----------------
__global__ __launch_bounds__(256) void k_zero_pool(float* pooled, float* cnt) {
    int i = blockIdx.x * 256 + threadIdx.x;
    if (i < NG * 128) pooled[i] = 0.f;
    if (i < NG) cnt[i] = 0.f;
}

__global__ __launch_bounds__(256) void k_pool_scatter(const float* __restrict__ h, const int* __restrict__ batch,
                                                      float* pooled, float* cnt) {
    int idx = blockIdx.x * 256 + threadIdx.x;
    if (idx >= NN * 128) return;
    int i = idx >> 7;
    int f = idx & 127;
    int g = batch[i];
    atomicAdd(&pooled[g * 128 + f], h[idx]);
    if (f == 0) atomicAdd(&cnt[g], 1.0f);
}

// ---------------- final MLP: relu(pooled/cnt @ fW1 + fb1) @ fW2 + fb2 ----------------
__global__ __launch_bounds__(64) void k_mlp(const float* __restrict__ pooled, const float* __restrict__ cnt,
                                            const float* __restrict__ fW1, const float* __restrict__ fb1,
                                            const float* __restrict__ fW2, const float* __restrict__ fb2,
                                            float* __restrict__ out) {
    int g = blockIdx.x;
    int j = threadIdx.x;                 // 0..63
    float inv = 1.0f / fmaxf(cnt[g], 1.0f);
    float acc = fb1[j];
#pragma unroll
    for (int k = 0; k < 128; ++k) acc += (pooled[g * 128 + k] * inv) * fW1[k * 64 + j];
    float hj = fmaxf(acc, 0.f) * fW2[j];
#pragma unroll
    for (int off = 32; off > 0; off >>= 1) hj += __shfl_down(hj, off, 64);
    if (j == 0) out[g] = hj + fb2[0];
}

extern "C" void kernel_launch(void* const* d_in, const int* in_sizes, int n_in,
                              void* d_out, int out_size, void* d_ws, size_t ws_size,
                              hipStream_t stream) {
    const float* x    = (const float*)d_in[0];
    const int*   src  = (const int*)d_in[1];
    const int*   dst  = (const int*)d_in[2];
    const int*   batch= (const int*)d_in[3];
    const float* W1   = (const float*)d_in[4];
    const float* b1   = (const float*)d_in[5];
    const float* g1   = (const float*)d_in[6];
    const float* be1  = (const float*)d_in[7];
    const float* W2   = (const float*)d_in[8];
    const float* b2   = (const float*)d_in[9];
    const float* g2   = (const float*)d_in[10];
    const float* be2  = (const float*)d_in[11];
    const float* fW1  = (const float*)d_in[12];
    const float* fb1  = (const float*)d_in[13];
    const float* fW2  = (const float*)d_in[14];
    const float* fb2  = (const float*)d_in[15];
    float* out = (float*)d_out;

    // workspace layout (floats)
    float* ws     = (float*)d_ws;
    float* deg    = ws;                      // NN
    float* dinv   = deg + NN;                // NN
    float* sums   = dinv + NN;               // 256
    float* pooled = sums + 256;              // NG*128
    float* cnt    = pooled + NG * 128;       // NG
    float* h1     = cnt + NG;                // NN*64
    float* agg1   = h1 + NN * 64;            // NN*64
    float* h2     = agg1 + NN * 64;          // NN*128
    float* agg2   = h1;                      // alias: h1+agg1 region (NN*128) is dead by then

    // ---- degree / norm ----
    k_init_deg<<<(NN + 255) / 256, 256, 0, stream>>>(deg);
    k_count_deg<<<(NE + 255) / 256, 256, 0, stream>>>(dst, deg);
    k_make_dinv<<<(NN + 255) / 256, 256, 0, stream>>>(deg, dinv);

    // ---- layer 1 ----
    k_mm1<<<(NN + 3) / 4, 256, 0, stream>>>(x, W1, h1);
    k_self_init<64><<<(NN * 64 + 255) / 256, 256, 0, stream>>>(h1, dinv, b1, agg1);
    k_edge_scatter<64, 6><<<((long long)NE * 64 + 255) / 256, 256, 0, stream>>>(h1, src, dst, dinv, agg1);
    k_zero_sums<<<1, 256, 0, stream>>>(sums);
    k_bn_stats<64><<<256, 256, 0, stream>>>(agg1, sums);
    k_bn_apply_relu<64><<<(NN * 64 + 255) / 256, 256, 0, stream>>>(agg1, sums, g1, be1);

    // ---- layer 2 ----
    k_mm2<<<(NN + 1) / 2, 256, 0, stream>>>(agg1, W2, h2);
    k_self_init<128><<<(NN * 128 + 255) / 256, 256, 0, stream>>>(h2, dinv, b2, agg2);
    k_edge_scatter<128, 7><<<((long long)NE * 128 + 255) / 256, 256, 0, stream>>>(h2, src, dst, dinv, agg2);
    k_zero_sums<<<1, 256, 0, stream>>>(sums);
    k_bn_stats<128><<<256, 256, 0, stream>>>(agg2, sums);
    k_bn_apply_relu<128><<<(NN * 128 + 255) / 256, 256, 0, stream>>>(agg2, sums, g2, be2);

    // ---- pooling + MLP head ----
    k_zero_pool<<<(NG * 128 + 255) / 256, 256, 0, stream>>>(pooled, cnt);
    k_pool_scatter<<<(NN * 128 + 255) / 256, 256, 0, stream>>>(agg2, batch, pooled, cnt);
    k_mlp<<<NG, 64, 0, stream>>>(pooled, cnt, fW1, fb1, fW2, fb2, out);
}

// Round 2
// 1112.921 us; speedup vs baseline: 2.3954x; 2.3954x over previous
//
#include <hip/hip_runtime.h>

#define NN 100000
#define NE 3200000
#define NG 2000
#define NPART 391              // (NN+255)/256 scan blocks
static constexpr float BN_EPS = 1e-5f;

// ---------------- CSR build ----------------
__global__ __launch_bounds__(256) void k_zero_int(int* p, int n) {
    int i = blockIdx.x * 256 + threadIdx.x;
    if (i < n) p[i] = 0;
}

__global__ __launch_bounds__(256) void k_hist(const int* __restrict__ dst, int* __restrict__ deg) {
    int e = blockIdx.x * 256 + threadIdx.x;
    if (e < NE) atomicAdd(&deg[dst[e]], 1);
}

// inclusive scan within 256-block; emit block totals
__global__ __launch_bounds__(256) void k_scan1(const int* __restrict__ deg, int* __restrict__ tmp,
                                               int* __restrict__ partials) {
    __shared__ int buf[256];
    int t = threadIdx.x;
    int i = blockIdx.x * 256 + t;
    buf[t] = (i < NN) ? deg[i] : 0;
    __syncthreads();
#pragma unroll
    for (int off = 1; off < 256; off <<= 1) {
        int a = (t >= off) ? buf[t - off] : 0;
        __syncthreads();
        buf[t] += a;
        __syncthreads();
    }
    if (i < NN) tmp[i] = buf[t];
    if (t == 255) partials[blockIdx.x] = buf[255];
}

// single-block inclusive scan of the partials
__global__ __launch_bounds__(512) void k_scan2(int* __restrict__ partials) {
    __shared__ int buf[512];
    int t = threadIdx.x;
    buf[t] = (t < NPART) ? partials[t] : 0;
    __syncthreads();
#pragma unroll
    for (int off = 1; off < 512; off <<= 1) {
        int a = (t >= off) ? buf[t - off] : 0;
        __syncthreads();
        buf[t] += a;
        __syncthreads();
    }
    if (t < NPART) partials[t] = buf[t];
}

// exclusive row_start = inclusive - own + prev block offset; init cursor
__global__ __launch_bounds__(256) void k_scan3(const int* __restrict__ deg, const int* __restrict__ tmp,
                                               const int* __restrict__ partials,
                                               int* __restrict__ row_start, int* __restrict__ cursor) {
    int i = blockIdx.x * 256 + threadIdx.x;
    if (i >= NN) return;
    int base = (blockIdx.x > 0) ? partials[blockIdx.x - 1] : 0;
    int excl = tmp[i] - deg[i] + base;
    row_start[i] = excl;
    cursor[i] = excl;
}

__global__ __launch_bounds__(256) void k_fill(const int* __restrict__ src, const int* __restrict__ dst,
                                              int* __restrict__ cursor, int* __restrict__ srcs) {
    int e = blockIdx.x * 256 + threadIdx.x;
    if (e >= NE) return;
    int d = dst[e];
    int pos = atomicAdd(&cursor[d], 1);
    srcs[pos] = src[e];
}

__global__ __launch_bounds__(256) void k_make_dinv(const int* __restrict__ deg, float* __restrict__ dinv) {
    int i = blockIdx.x * 256 + threadIdx.x;
    if (i < NN) dinv[i] = rsqrtf((float)(deg[i] + 1));   // +1 self-loop, always >=1
}

// ---------------- layer-1 aggregation over raw x (F=10, padded 16) ----------------
// wave per dst node; 4 edge-groups x 16 feature-lanes
__global__ __launch_bounds__(256) void k_gather1(const float* __restrict__ x, const int* __restrict__ srcs,
                                                 const int* __restrict__ row_start, const int* __restrict__ deg,
                                                 const float* __restrict__ dinv, float* __restrict__ aggx) {
    int lane = threadIdx.x & 63;
    int wid  = threadIdx.x >> 6;
    int d = blockIdx.x * 4 + wid;
    if (d >= NN) return;
    int g = lane >> 4;        // 0..3 edge group
    int f = lane & 15;        // 0..15 (valid < 10)
    int start = row_start[d];
    int cnt   = deg[d];
    float acc = 0.f;
    for (int k = g; k < cnt; k += 4) {
        int s = srcs[start + k];
        float w = dinv[s];
        acc += (f < 10 ? x[s * 10 + f] : 0.f) * w;
    }
    acc += __shfl_xor(acc, 16, 64);
    acc += __shfl_xor(acc, 32, 64);
    float dd = dinv[d];
    if (g == 0 && f < 10) {
        aggx[d * 16 + f] = dd * acc + dd * dd * x[d * 10 + f];
    }
}

// ---------------- h1 = aggx @ W1 + b1   (N x 10) @ (10 x 64) ----------------
__global__ __launch_bounds__(256) void k_mm1b(const float* __restrict__ aggx, const float* __restrict__ W,
                                              const float* __restrict__ b, float* __restrict__ h) {
    int row = blockIdx.x * 4 + (threadIdx.x >> 6);
    int f   = threadIdx.x & 63;
    if (row >= NN) return;
    float acc = b[f];
#pragma unroll
    for (int k = 0; k < 10; ++k) acc += aggx[row * 16 + k] * W[k * 64 + f];
    h[row * 64 + f] = acc;
}

// ---------------- layer-2 aggregation over h1r (F=64) ----------------
__global__ __launch_bounds__(256) void k_gather2(const float* __restrict__ h, const int* __restrict__ srcs,
                                                 const int* __restrict__ row_start, const int* __restrict__ deg,
                                                 const float* __restrict__ dinv, float* __restrict__ aggh) {
    int f   = threadIdx.x & 63;
    int wid = threadIdx.x >> 6;
    int d = blockIdx.x * 4 + wid;
    if (d >= NN) return;
    int start = row_start[d];
    int cnt   = deg[d];
    float acc0 = 0.f, acc1 = 0.f;
    int k = 0;
    for (; k + 2 <= cnt; k += 2) {
        int s0 = srcs[start + k];
        int s1 = srcs[start + k + 1];
        acc0 += h[s0 * 64 + f] * dinv[s0];
        acc1 += h[s1 * 64 + f] * dinv[s1];
    }
    if (k < cnt) {
        int s = srcs[start + k];
        acc0 += h[s * 64 + f] * dinv[s];
    }
    float dd = dinv[d];
    aggh[d * 64 + f] = dd * (acc0 + acc1) + dd * dd * h[d * 64 + f];
}

// ---------------- batchnorm ----------------
__global__ __launch_bounds__(256) void k_zero_sums(float* sums) {
    if (blockIdx.x == 0) sums[threadIdx.x] = 0.f;
}

template <int F>
__global__ __launch_bounds__(256) void k_bn_stats(const float* __restrict__ agg, float* __restrict__ sums) {
    __shared__ float ls[256];
    __shared__ float lq[256];
    int t = threadIdx.x;
    int T = gridDim.x * 256;
    float s = 0.f, q = 0.f;
    for (int idx = blockIdx.x * 256 + t; idx < NN * F; idx += T) {
        float v = agg[idx];
        s += v;
        q += v * v;
    }
    ls[t] = s;
    lq[t] = q;
    __syncthreads();
    if (t < F) {
        float S = 0.f, Q = 0.f;
#pragma unroll
        for (int j = t; j < 256; j += F) { S += ls[j]; Q += lq[j]; }
        atomicAdd(&sums[t], S);
        atomicAdd(&sums[F + t], Q);
    }
}

template <int F>
__global__ __launch_bounds__(256) void k_bn_apply_relu(float* __restrict__ agg, const float* __restrict__ sums,
                                                       const float* __restrict__ g, const float* __restrict__ be) {
    int idx = blockIdx.x * 256 + threadIdx.x;
    if (idx >= NN * F) return;
    int f = idx & (F - 1);
    const float invn = 1.0f / (float)NN;
    float mu  = sums[f] * invn;
    float var = sums[F + f] * invn - mu * mu;
    float sc  = g[f] * rsqrtf(var + BN_EPS);
    float v   = (agg[idx] - mu) * sc + be[f];
    agg[idx]  = fmaxf(v, 0.f);
}

// ---------------- h2 = aggh @ W2 + b2   (N x 64) @ (64 x 128) ----------------
__global__ __launch_bounds__(256) void k_mm2b(const float* __restrict__ hin, const float* __restrict__ W,
                                              const float* __restrict__ b, float* __restrict__ hout) {
    __shared__ float row[2][64];
    int r = threadIdx.x >> 7;
    int f = threadIdx.x & 127;
    int i = blockIdx.x * 2 + r;
    if (f < 64 && i < NN) row[r][f] = hin[i * 64 + f];
    __syncthreads();
    if (i >= NN) return;
    float acc = b[f];
#pragma unroll
    for (int k = 0; k < 64; ++k) acc += row[r][k] * W[k * 128 + f];
    hout[i * 128 + f] = acc;
}

// ---------------- pooling ----------------
__global__ __launch_bounds__(256) void k_zero_pool(float* pooled, float* cnt) {
    int i = blockIdx.x * 256 + threadIdx.x;
    if (i < NG * 128) pooled[i] = 0.f;
    if (i < NG) cnt[i] = 0.f;
}

__global__ __launch_bounds__(256) void k_pool_scatter(const float* __restrict__ h, const int* __restrict__ batch,
                                                      float* pooled, float* cnt) {
    int idx = blockIdx.x * 256 + threadIdx.x;
    if (idx >= NN * 128) return;
    int i = idx >> 7;
    int f = idx & 127;
    int g = batch[i];
    atomicAdd(&pooled[g * 128 + f], h[idx]);
    if (f == 0) atomicAdd(&cnt[g], 1.0f);
}

// ---------------- final MLP ----------------
__global__ __launch_bounds__(64) void k_mlp(const float* __restrict__ pooled, const float* __restrict__ cnt,
                                            const float* __restrict__ fW1, const float* __restrict__ fb1,
                                            const float* __restrict__ fW2, const float* __restrict__ fb2,
                                            float* __restrict__ out) {
    int g = blockIdx.x;
    int j = threadIdx.x;
    float inv = 1.0f / fmaxf(cnt[g], 1.0f);
    float acc = fb1[j];
#pragma unroll
    for (int k = 0; k < 128; ++k) acc += (pooled[g * 128 + k] * inv) * fW1[k * 64 + j];
    float hj = fmaxf(acc, 0.f) * fW2[j];
#pragma unroll
    for (int off = 32; off > 0; off >>= 1) hj += __shfl_down(hj, off, 64);
    if (j == 0) out[g] = hj + fb2[0];
}

extern "C" void kernel_launch(void* const* d_in, const int* in_sizes, int n_in,
                              void* d_out, int out_size, void* d_ws, size_t ws_size,
                              hipStream_t stream) {
    const float* x    = (const float*)d_in[0];
    const int*   src  = (const int*)d_in[1];
    const int*   dst  = (const int*)d_in[2];
    const int*   batch= (const int*)d_in[3];
    const float* W1   = (const float*)d_in[4];
    const float* b1   = (const float*)d_in[5];
    const float* g1   = (const float*)d_in[6];
    const float* be1  = (const float*)d_in[7];
    const float* W2   = (const float*)d_in[8];
    const float* b2   = (const float*)d_in[9];
    const float* g2   = (const float*)d_in[10];
    const float* be2  = (const float*)d_in[11];
    const float* fW1  = (const float*)d_in[12];
    const float* fb1  = (const float*)d_in[13];
    const float* fW2  = (const float*)d_in[14];
    const float* fb2  = (const float*)d_in[15];
    float* out = (float*)d_out;

    // ---- workspace layout (103.6 MB total, lifetime-aliased) ----
    float* ws        = (float*)d_ws;
    int*   deg_i     = (int*)ws;                   // NN          (live all)
    int*   row_start = deg_i + NN;                 // NN          (live all)
    float* dinv      = (float*)(row_start + NN);   // NN          (live all)
    float* h1        = dinv + NN;                  // NN*64       (dead after gather2)
    float* aggh      = h1 + NN * 64;               // NN*64       (live gather2..mm2b)
    float* h2        = aggh + NN * 64;             // NN*128
    // aliases inside aggh (all dead before gather2 writes aggh):
    int*   tmp_scan  = (int*)aggh;                 // NN   (scan phase)
    int*   cursor    = tmp_scan + NN;              // NN   (fill phase)
    int*   partials  = cursor + NN;                // 512  (scan phase)
    float* sums      = (float*)aggh + 3 * NN;      // 256  (BN1 pre-gather2; BN2 post-mm2b)
    // aliases inside h2 (h2 proper written at mm2b, after these die):
    float* aggx      = h2;                         // NN*16 (gather1..mm1b)
    int*   srcs      = (int*)(h2 + NN * 16);       // NE    (fill..gather2)
    // aliases inside h1 (dead after gather2; pool runs after BN2):
    float* pooled    = h1;                         // NG*128
    float* cntf      = h1 + NG * 128;              // NG

    // ---- CSR build + norms ----
    k_zero_int<<<(NN + 255) / 256, 256, 0, stream>>>(deg_i, NN);
    k_hist<<<(NE + 255) / 256, 256, 0, stream>>>(dst, deg_i);
    k_make_dinv<<<(NN + 255) / 256, 256, 0, stream>>>(deg_i, dinv);
    k_scan1<<<NPART, 256, 0, stream>>>(deg_i, tmp_scan, partials);
    k_scan2<<<1, 512, 0, stream>>>(partials);
    k_scan3<<<NPART, 256, 0, stream>>>(deg_i, tmp_scan, partials, row_start, cursor);
    k_fill<<<(NE + 255) / 256, 256, 0, stream>>>(src, dst, cursor, srcs);

    // ---- layer 1: aggregate x (F=10) then transform ----
    k_gather1<<<(NN + 3) / 4, 256, 0, stream>>>(x, srcs, row_start, deg_i, dinv, aggx);
    k_mm1b<<<(NN + 3) / 4, 256, 0, stream>>>(aggx, W1, b1, h1);
    k_zero_sums<<<1, 256, 0, stream>>>(sums);
    k_bn_stats<64><<<256, 256, 0, stream>>>(h1, sums);
    k_bn_apply_relu<64><<<(NN * 64 + 255) / 256, 256, 0, stream>>>(h1, sums, g1, be1);

    // ---- layer 2: aggregate h1r (F=64) then transform ----
    k_gather2<<<(NN + 3) / 4, 256, 0, stream>>>(h1, srcs, row_start, deg_i, dinv, aggh);
    k_mm2b<<<(NN + 1) / 2, 256, 0, stream>>>(aggh, W2, b2, h2);
    k_zero_sums<<<1, 256, 0, stream>>>(sums);
    k_bn_stats<128><<<256, 256, 0, stream>>>(h2, sums);
    k_bn_apply_relu<128><<<(NN * 128 + 255) / 256, 256, 0, stream>>>(h2, sums, g2, be2);

    // ---- pooling + MLP head ----
    k_zero_pool<<<(NG * 128 + 255) / 256, 256, 0, stream>>>(pooled, cntf);
    k_pool_scatter<<<(NN * 128 + 255) / 256, 256, 0, stream>>>(h2, batch, pooled, cntf);
    k_mlp<<<NG, 64, 0, stream>>>(pooled, cntf, fW1, fb1, fW2, fb2, out);
}

// Round 3
// 882.073 us; speedup vs baseline: 3.0224x; 1.2617x over previous
//
#include <hip/hip_runtime.h>

#define NN 100000
#define NE 3200000
#define NG 2000
#define NPART 391              // (NN+255)/256 scan blocks
#define NB 196                 // dst buckets of 512 nodes
#define BKT_SH 9
#define EPT 16                 // edges per thread in k_bucket
static constexpr float BN_EPS = 1e-5f;

// ---------------- CSR build ----------------
__global__ __launch_bounds__(256) void k_zero_int(int* p, int n) {
    int i = blockIdx.x * 256 + threadIdx.x;
    if (i < n) p[i] = 0;
}

__global__ __launch_bounds__(256) void k_hist(const int* __restrict__ dst, int* __restrict__ deg) {
    int e = blockIdx.x * 256 + threadIdx.x;
    if (e < NE) atomicAdd(&deg[dst[e]], 1);
}

// inclusive scan within 256-block; emit block totals
__global__ __launch_bounds__(256) void k_scan1(const int* __restrict__ deg, int* __restrict__ tmp,
                                               int* __restrict__ partials) {
    __shared__ int buf[256];
    int t = threadIdx.x;
    int i = blockIdx.x * 256 + t;
    buf[t] = (i < NN) ? deg[i] : 0;
    __syncthreads();
#pragma unroll
    for (int off = 1; off < 256; off <<= 1) {
        int a = (t >= off) ? buf[t - off] : 0;
        __syncthreads();
        buf[t] += a;
        __syncthreads();
    }
    if (i < NN) tmp[i] = buf[t];
    if (t == 255) partials[blockIdx.x] = buf[255];
}

// single-block inclusive scan of the partials
__global__ __launch_bounds__(512) void k_scan2(int* __restrict__ partials) {
    __shared__ int buf[512];
    int t = threadIdx.x;
    buf[t] = (t < NPART) ? partials[t] : 0;
    __syncthreads();
#pragma unroll
    for (int off = 1; off < 512; off <<= 1) {
        int a = (t >= off) ? buf[t - off] : 0;
        __syncthreads();
        buf[t] += a;
        __syncthreads();
    }
    if (t < NPART) partials[t] = buf[t];
}

// exclusive row_start; init cursor, bucket cursors, dinv
__global__ __launch_bounds__(256) void k_scan3(const int* __restrict__ deg, const int* __restrict__ tmp,
                                               const int* __restrict__ partials,
                                               int* __restrict__ row_start, int* __restrict__ cursor,
                                               int* __restrict__ bcur, float* __restrict__ dinv) {
    int i = blockIdx.x * 256 + threadIdx.x;
    if (i >= NN) return;
    int base = (blockIdx.x > 0) ? partials[blockIdx.x - 1] : 0;
    int excl = tmp[i] - deg[i] + base;
    row_start[i] = excl;
    cursor[i] = excl;
    if ((i & 511) == 0) bcur[i >> BKT_SH] = excl;
    dinv[i] = rsqrtf((float)(deg[i] + 1));   // +1 self-loop
}

// pass A: bucket-partition edges into staging, dense contiguous runs per block
__global__ __launch_bounds__(256) void k_bucket(const int* __restrict__ src, const int* __restrict__ dst,
                                                int* __restrict__ bcur, unsigned long long* __restrict__ stage) {
    __shared__ int cnt[NB];
    __shared__ int base[NB];
    int t = threadIdx.x;
    long long e0 = (long long)blockIdx.x * (256 * EPT);
    int es[EPT], ed[EPT];
#pragma unroll
    for (int i = 0; i < EPT; ++i) {
        long long e = e0 + t + i * 256;
        if (e < NE) { es[i] = src[e]; ed[i] = dst[e]; }
        else ed[i] = -1;
    }
    for (int i = t; i < NB; i += 256) cnt[i] = 0;
    __syncthreads();
#pragma unroll
    for (int i = 0; i < EPT; ++i)
        if (ed[i] >= 0) atomicAdd(&cnt[ed[i] >> BKT_SH], 1);
    __syncthreads();
    for (int i = t; i < NB; i += 256) {
        int c = cnt[i];
        base[i] = c ? atomicAdd(&bcur[i], c) : 0;
    }
    __syncthreads();
    for (int i = t; i < NB; i += 256) cnt[i] = 0;
    __syncthreads();
#pragma unroll
    for (int i = 0; i < EPT; ++i) {
        if (ed[i] >= 0) {
            int b = ed[i] >> BKT_SH;
            int pos = base[b] + atomicAdd(&cnt[b], 1);
            stage[pos] = ((unsigned long long)(unsigned)ed[i] << 32) | (unsigned)es[i];
        }
    }
}

// pass B: scatter within L2-resident bucket windows
__global__ __launch_bounds__(256) void k_fill2(const unsigned long long* __restrict__ stage,
                                               int* __restrict__ cursor, int* __restrict__ srcs) {
    int e = blockIdx.x * 256 + threadIdx.x;
    if (e >= NE) return;
    unsigned long long p = stage[e];
    int d = (int)(p >> 32);
    int s = (int)(p & 0xffffffffu);
    int pos = atomicAdd(&cursor[d], 1);
    srcs[pos] = s;
}

// ---------------- layer-1 aggregation over raw x (F=10, padded 16) ----------------
__global__ __launch_bounds__(256) void k_gather1(const float* __restrict__ x, const int* __restrict__ srcs,
                                                 const int* __restrict__ row_start, const int* __restrict__ deg,
                                                 const float* __restrict__ dinv, float* __restrict__ aggx) {
    int lane = threadIdx.x & 63;
    int wid  = threadIdx.x >> 6;
    int d = blockIdx.x * 4 + wid;
    if (d >= NN) return;
    int g = lane >> 4;        // 0..3 edge group
    int f = lane & 15;        // 0..15 (valid < 10)
    int start = row_start[d];
    int cnt   = deg[d];
    float acc = 0.f;
    for (int k = g; k < cnt; k += 4) {
        int s = srcs[start + k];
        float w = dinv[s];
        acc += (f < 10 ? x[s * 10 + f] : 0.f) * w;
    }
    acc += __shfl_xor(acc, 16, 64);
    acc += __shfl_xor(acc, 32, 64);
    float dd = dinv[d];
    if (g == 0 && f < 10) {
        aggx[d * 16 + f] = dd * acc + dd * dd * x[d * 10 + f];
    }
}

// ---------------- h1 = aggx @ W1 + b1 ----------------
__global__ __launch_bounds__(256) void k_mm1b(const float* __restrict__ aggx, const float* __restrict__ W,
                                              const float* __restrict__ b, float* __restrict__ h) {
    int row = blockIdx.x * 4 + (threadIdx.x >> 6);
    int f   = threadIdx.x & 63;
    if (row >= NN) return;
    float acc = b[f];
#pragma unroll
    for (int k = 0; k < 10; ++k) acc += aggx[row * 16 + k] * W[k * 64 + f];
    h[row * 64 + f] = acc;
}

// ---------------- layer-2 aggregation over h1r (F=64) ----------------
__global__ __launch_bounds__(256) void k_gather2(const float* __restrict__ h, const int* __restrict__ srcs,
                                                 const int* __restrict__ row_start, const int* __restrict__ deg,
                                                 const float* __restrict__ dinv, float* __restrict__ aggh) {
    int f   = threadIdx.x & 63;
    int wid = threadIdx.x >> 6;
    int d = blockIdx.x * 4 + wid;
    if (d >= NN) return;
    int start = row_start[d];
    int cnt   = deg[d];
    float acc0 = 0.f, acc1 = 0.f;
    int k = 0;
    for (; k + 2 <= cnt; k += 2) {
        int s0 = srcs[start + k];
        int s1 = srcs[start + k + 1];
        acc0 += h[s0 * 64 + f] * dinv[s0];
        acc1 += h[s1 * 64 + f] * dinv[s1];
    }
    if (k < cnt) {
        int s = srcs[start + k];
        acc0 += h[s * 64 + f] * dinv[s];
    }
    float dd = dinv[d];
    aggh[d * 64 + f] = dd * (acc0 + acc1) + dd * dd * h[d * 64 + f];
}

// ---------------- batchnorm ----------------
__global__ __launch_bounds__(256) void k_zero_sums(float* sums) {
    if (blockIdx.x == 0) sums[threadIdx.x] = 0.f;
}

template <int F>
__global__ __launch_bounds__(256) void k_bn_stats(const float* __restrict__ agg, float* __restrict__ sums) {
    __shared__ float ls[256];
    __shared__ float lq[256];
    int t = threadIdx.x;
    int T = gridDim.x * 256;
    float s = 0.f, q = 0.f;
    for (int idx = blockIdx.x * 256 + t; idx < NN * F; idx += T) {
        float v = agg[idx];
        s += v;
        q += v * v;
    }
    ls[t] = s;
    lq[t] = q;
    __syncthreads();
    if (t < F) {
        float S = 0.f, Q = 0.f;
#pragma unroll
        for (int j = t; j < 256; j += F) { S += ls[j]; Q += lq[j]; }
        atomicAdd(&sums[t], S);
        atomicAdd(&sums[F + t], Q);
    }
}

template <int F>
__global__ __launch_bounds__(256) void k_bn_apply_relu(float* __restrict__ agg, const float* __restrict__ sums,
                                                       const float* __restrict__ g, const float* __restrict__ be) {
    int idx = blockIdx.x * 256 + threadIdx.x;
    if (idx >= NN * F) return;
    int f = idx & (F - 1);
    const float invn = 1.0f / (float)NN;
    float mu  = sums[f] * invn;
    float var = sums[F + f] * invn - mu * mu;
    float sc  = g[f] * rsqrtf(var + BN_EPS);
    float v   = (agg[idx] - mu) * sc + be[f];
    agg[idx]  = fmaxf(v, 0.f);
}

// ---------------- h2 = aggh @ W2 + b2 ----------------
__global__ __launch_bounds__(256) void k_mm2b(const float* __restrict__ hin, const float* __restrict__ W,
                                              const float* __restrict__ b, float* __restrict__ hout) {
    __shared__ float row[2][64];
    int r = threadIdx.x >> 7;
    int f = threadIdx.x & 127;
    int i = blockIdx.x * 2 + r;
    if (f < 64 && i < NN) row[r][f] = hin[i * 64 + f];
    __syncthreads();
    if (i >= NN) return;
    float acc = b[f];
#pragma unroll
    for (int k = 0; k < 64; ++k) acc += row[r][k] * W[k * 128 + f];
    hout[i * 128 + f] = acc;
}

// ---------------- pooling ----------------
__global__ __launch_bounds__(256) void k_zero_pool(float* pooled, float* cnt) {
    int i = blockIdx.x * 256 + threadIdx.x;
    if (i < NG * 128) pooled[i] = 0.f;
    if (i < NG) cnt[i] = 0.f;
}

// segmented pooling: batch is sorted, accumulate runs in registers
__global__ __launch_bounds__(128) void k_pool_seg(const float* __restrict__ h, const int* __restrict__ batch,
                                                  float* __restrict__ pooled, float* __restrict__ cnt) {
    int f = threadIdx.x;                 // 0..127
    int i0 = blockIdx.x * 128;
    int iend = min(i0 + 128, NN);
    if (i0 >= NN) return;
    int gp = batch[i0];
    float acc = 0.f;
    int run = 0;
    for (int i = i0; i < iend; ++i) {
        int g = batch[i];
        if (g != gp) {
            atomicAdd(&pooled[gp * 128 + f], acc);
            if (f == 0) atomicAdd(&cnt[gp], (float)run);
            acc = 0.f; run = 0; gp = g;
        }
        acc += h[(long long)i * 128 + f];
        run++;
    }
    atomicAdd(&pooled[gp * 128 + f], acc);
    if (f == 0) atomicAdd(&cnt[gp], (float)run);
}

// ---------------- final MLP ----------------
__global__ __launch_bounds__(64) void k_mlp(const float* __restrict__ pooled, const float* __restrict__ cnt,
                                            const float* __restrict__ fW1, const float* __restrict__ fb1,
                                            const float* __restrict__ fW2, const float* __restrict__ fb2,
                                            float* __restrict__ out) {
    int g = blockIdx.x;
    int j = threadIdx.x;
    float inv = 1.0f / fmaxf(cnt[g], 1.0f);
    float acc = fb1[j];
#pragma unroll
    for (int k = 0; k < 128; ++k) acc += (pooled[g * 128 + k] * inv) * fW1[k * 64 + j];
    float hj = fmaxf(acc, 0.f) * fW2[j];
#pragma unroll
    for (int off = 32; off > 0; off >>= 1) hj += __shfl_down(hj, off, 64);
    if (j == 0) out[g] = hj + fb2[0];
}

extern "C" void kernel_launch(void* const* d_in, const int* in_sizes, int n_in,
                              void* d_out, int out_size, void* d_ws, size_t ws_size,
                              hipStream_t stream) {
    const float* x    = (const float*)d_in[0];
    const int*   src  = (const int*)d_in[1];
    const int*   dst  = (const int*)d_in[2];
    const int*   batch= (const int*)d_in[3];
    const float* W1   = (const float*)d_in[4];
    const float* b1   = (const float*)d_in[5];
    const float* g1   = (const float*)d_in[6];
    const float* be1  = (const float*)d_in[7];
    const float* W2   = (const float*)d_in[8];
    const float* b2   = (const float*)d_in[9];
    const float* g2   = (const float*)d_in[10];
    const float* be2  = (const float*)d_in[11];
    const float* fW1  = (const float*)d_in[12];
    const float* fb1  = (const float*)d_in[13];
    const float* fW2  = (const float*)d_in[14];
    const float* fb2  = (const float*)d_in[15];
    float* out = (float*)d_out;

    // ---- workspace layout (104.0 MB, lifetime-aliased) ----
    float* ws        = (float*)d_ws;
    int*   deg_i     = (int*)ws;                   // NN
    int*   row_start = deg_i + NN;                 // NN
    float* dinv      = (float*)(row_start + NN);   // NN
    int*   cursor    = (int*)(dinv + NN);          // NN
    int*   bcur      = cursor + NN;                // 256
    float* sums      = (float*)(bcur + 256);       // 256
    float* h1        = sums + 256;                 // NN*64 (dead after gather2)
    float* stage_f   = h1 + NN * 64;               // NN*64 == NE*2 (stage; later aggh)
    float* h2        = stage_f + NN * 64;          // NN*128
    // aliases in stage region (dead before k_bucket writes stage):
    int*   tmp_scan  = (int*)stage_f;              // NN
    int*   partials  = tmp_scan + NN;              // 512
    unsigned long long* stage = (unsigned long long*)stage_f;   // NE (8B)
    float* aggh      = stage_f;                    // NN*64 (written by gather2, after fill2)
    // aliases in h2 region (h2 written at mm2b, after these die):
    float* aggx      = h2;                         // NN*16 (gather1..mm1b)
    int*   srcs      = (int*)(h2 + NN * 16);       // NE    (fill2..gather2)
    // aliases in h1 region (dead after gather2):
    float* pooled    = h1;                         // NG*128
    float* cntf      = h1 + NG * 128;              // NG

    // ---- CSR build + norms ----
    k_zero_int<<<(NN + 255) / 256, 256, 0, stream>>>(deg_i, NN);
    k_hist<<<(NE + 255) / 256, 256, 0, stream>>>(dst, deg_i);
    k_scan1<<<NPART, 256, 0, stream>>>(deg_i, tmp_scan, partials);
    k_scan2<<<1, 512, 0, stream>>>(partials);
    k_scan3<<<NPART, 256, 0, stream>>>(deg_i, tmp_scan, partials, row_start, cursor, bcur, dinv);
    k_bucket<<<(NE + 256 * EPT - 1) / (256 * EPT), 256, 0, stream>>>(src, dst, bcur, stage);
    k_fill2<<<(NE + 255) / 256, 256, 0, stream>>>(stage, cursor, srcs);

    // ---- layer 1: aggregate x (F=10) then transform ----
    k_gather1<<<(NN + 3) / 4, 256, 0, stream>>>(x, srcs, row_start, deg_i, dinv, aggx);
    k_mm1b<<<(NN + 3) / 4, 256, 0, stream>>>(aggx, W1, b1, h1);
    k_zero_sums<<<1, 256, 0, stream>>>(sums);
    k_bn_stats<64><<<256, 256, 0, stream>>>(h1, sums);
    k_bn_apply_relu<64><<<(NN * 64 + 255) / 256, 256, 0, stream>>>(h1, sums, g1, be1);

    // ---- layer 2: aggregate h1r (F=64) then transform ----
    k_gather2<<<(NN + 3) / 4, 256, 0, stream>>>(h1, srcs, row_start, deg_i, dinv, aggh);
    k_mm2b<<<(NN + 1) / 2, 256, 0, stream>>>(aggh, W2, b2, h2);
    k_zero_sums<<<1, 256, 0, stream>>>(sums);
    k_bn_stats<128><<<256, 256, 0, stream>>>(h2, sums);
    k_bn_apply_relu<128><<<(NN * 128 + 255) / 256, 256, 0, stream>>>(h2, sums, g2, be2);

    // ---- pooling + MLP head ----
    k_zero_pool<<<(NG * 128 + 255) / 256, 256, 0, stream>>>(pooled, cntf);
    k_pool_seg<<<(NN + 127) / 128, 128, 0, stream>>>(h2, batch, pooled, cntf);
    k_mlp<<<NG, 64, 0, stream>>>(pooled, cntf, fW1, fb1, fW2, fb2, out);
}

// Round 4
// 748.915 us; speedup vs baseline: 3.5597x; 1.1778x over previous
//
#include <hip/hip_runtime.h>
#include <hip/hip_fp16.h>

#define NN 100000
#define NE 3200000
#define NG 2000
#define NPART 391              // (NN+255)/256 scan blocks
#define NB 196                 // dst buckets of 512 nodes
#define BKT_SH 9
#define EPT 16                 // edges per thread in k_bucket
static constexpr float BN_EPS = 1e-5f;

// ---------------- CSR build ----------------
__global__ __launch_bounds__(256) void k_zero_int(int* p, int n) {
    int i = blockIdx.x * 256 + threadIdx.x;
    if (i < n) p[i] = 0;
}

__global__ __launch_bounds__(256) void k_hist(const int* __restrict__ dst, int* __restrict__ deg) {
    int e = blockIdx.x * 256 + threadIdx.x;
    if (e < NE) atomicAdd(&deg[dst[e]], 1);
}

__global__ __launch_bounds__(256) void k_scan1(const int* __restrict__ deg, int* __restrict__ tmp,
                                               int* __restrict__ partials) {
    __shared__ int buf[256];
    int t = threadIdx.x;
    int i = blockIdx.x * 256 + t;
    buf[t] = (i < NN) ? deg[i] : 0;
    __syncthreads();
#pragma unroll
    for (int off = 1; off < 256; off <<= 1) {
        int a = (t >= off) ? buf[t - off] : 0;
        __syncthreads();
        buf[t] += a;
        __syncthreads();
    }
    if (i < NN) tmp[i] = buf[t];
    if (t == 255) partials[blockIdx.x] = buf[255];
}

__global__ __launch_bounds__(512) void k_scan2(int* __restrict__ partials) {
    __shared__ int buf[512];
    int t = threadIdx.x;
    buf[t] = (t < NPART) ? partials[t] : 0;
    __syncthreads();
#pragma unroll
    for (int off = 1; off < 512; off <<= 1) {
        int a = (t >= off) ? buf[t - off] : 0;
        __syncthreads();
        buf[t] += a;
        __syncthreads();
    }
    if (t < NPART) partials[t] = buf[t];
}

__global__ __launch_bounds__(256) void k_scan3(const int* __restrict__ deg, const int* __restrict__ tmp,
                                               const int* __restrict__ partials,
                                               int* __restrict__ row_start, int* __restrict__ cursor,
                                               int* __restrict__ bcur, float* __restrict__ dinv) {
    int i = blockIdx.x * 256 + threadIdx.x;
    if (i >= NN) return;
    int base = (blockIdx.x > 0) ? partials[blockIdx.x - 1] : 0;
    int excl = tmp[i] - deg[i] + base;
    row_start[i] = excl;
    cursor[i] = excl;
    if ((i & 511) == 0) bcur[i >> BKT_SH] = excl;
    dinv[i] = rsqrtf((float)(deg[i] + 1));   // +1 self-loop
}

__global__ __launch_bounds__(256) void k_bucket(const int* __restrict__ src, const int* __restrict__ dst,
                                                int* __restrict__ bcur, unsigned long long* __restrict__ stage) {
    __shared__ int cnt[NB];
    __shared__ int base[NB];
    int t = threadIdx.x;
    long long e0 = (long long)blockIdx.x * (256 * EPT);
    int es[EPT], ed[EPT];
#pragma unroll
    for (int i = 0; i < EPT; ++i) {
        long long e = e0 + t + i * 256;
        if (e < NE) { es[i] = src[e]; ed[i] = dst[e]; }
        else ed[i] = -1;
    }
    for (int i = t; i < NB; i += 256) cnt[i] = 0;
    __syncthreads();
#pragma unroll
    for (int i = 0; i < EPT; ++i)
        if (ed[i] >= 0) atomicAdd(&cnt[ed[i] >> BKT_SH], 1);
    __syncthreads();
    for (int i = t; i < NB; i += 256) {
        int c = cnt[i];
        base[i] = c ? atomicAdd(&bcur[i], c) : 0;
    }
    __syncthreads();
    for (int i = t; i < NB; i += 256) cnt[i] = 0;
    __syncthreads();
#pragma unroll
    for (int i = 0; i < EPT; ++i) {
        if (ed[i] >= 0) {
            int b = ed[i] >> BKT_SH;
            int pos = base[b] + atomicAdd(&cnt[b], 1);
            stage[pos] = ((unsigned long long)(unsigned)ed[i] << 32) | (unsigned)es[i];
        }
    }
}

__global__ __launch_bounds__(256) void k_fill2(const unsigned long long* __restrict__ stage,
                                               int* __restrict__ cursor, int* __restrict__ srcs) {
    int e = blockIdx.x * 256 + threadIdx.x;
    if (e >= NE) return;
    unsigned long long p = stage[e];
    int d = (int)(p >> 32);
    int s = (int)(p & 0xffffffffu);
    int pos = atomicAdd(&cursor[d], 1);
    srcs[pos] = s;
}

// ---------------- xh = fp16(x * dinv), padded to 16 ----------------
__global__ __launch_bounds__(256) void k_xcast(const float* __restrict__ x, const float* __restrict__ dinv,
                                               __half2* __restrict__ xh2) {
    int idx = blockIdx.x * 256 + threadIdx.x;
    if (idx >= NN * 8) return;
    int i = idx >> 3;
    int c = idx & 7;
    int f0 = 2 * c, f1 = 2 * c + 1;
    float dv = dinv[i];
    float v0 = (f0 < 10) ? x[i * 10 + f0] * dv : 0.f;
    float v1 = (f1 < 10) ? x[i * 10 + f1] * dv : 0.f;
    xh2[idx] = __floats2half2_rn(v0, v1);
}

// ---------------- layer-1 aggregation (rows of 8 half2 = 32B) ----------------
__global__ __launch_bounds__(256) void k_gather1(const __half2* __restrict__ xh2, const int* __restrict__ srcs,
                                                 const int* __restrict__ row_start, const int* __restrict__ deg,
                                                 const float* __restrict__ dinv, float2* __restrict__ aggx2) {
    int lane = threadIdx.x & 63;
    int wid  = threadIdx.x >> 6;
    int d = blockIdx.x * 4 + wid;
    if (d >= NN) return;
    int g = lane >> 3;        // 0..7 edge group
    int c = lane & 7;         // half2 chunk
    int start = row_start[d];
    int cnt   = deg[d];
    float ax = 0.f, ay = 0.f;
    int k = g;
    for (; k + 8 < cnt; k += 16) {
        int s0 = srcs[start + k];
        int s1 = srcs[start + k + 8];
        float2 v0 = __half22float2(xh2[s0 * 8 + c]);
        float2 v1 = __half22float2(xh2[s1 * 8 + c]);
        ax += v0.x + v1.x;
        ay += v0.y + v1.y;
    }
    if (k < cnt) {
        int s = srcs[start + k];
        float2 v = __half22float2(xh2[s * 8 + c]);
        ax += v.x; ay += v.y;
    }
    if (g == 0) {   // self-loop term: dinv[d]*x[d] already folded into xh
        float2 v = __half22float2(xh2[d * 8 + c]);
        ax += v.x; ay += v.y;
    }
#pragma unroll
    for (int m = 8; m < 64; m <<= 1) {
        ax += __shfl_xor(ax, m, 64);
        ay += __shfl_xor(ay, m, 64);
    }
    if (g == 0) {
        float dd = dinv[d];
        aggx2[d * 8 + c] = make_float2(dd * ax, dd * ay);
    }
}

// ---------------- h1 = aggx @ W1 + b1 ----------------
__global__ __launch_bounds__(256) void k_mm1b(const float* __restrict__ aggx, const float* __restrict__ W,
                                              const float* __restrict__ b, float* __restrict__ h) {
    int row = blockIdx.x * 4 + (threadIdx.x >> 6);
    int f   = threadIdx.x & 63;
    if (row >= NN) return;
    float acc = b[f];
#pragma unroll
    for (int k = 0; k < 10; ++k) acc += aggx[row * 16 + k] * W[k * 64 + f];
    h[row * 64 + f] = acc;
}

// ---------------- batchnorm stats ----------------
__global__ __launch_bounds__(256) void k_zero_sums(float* sums) {
    if (blockIdx.x == 0) sums[threadIdx.x] = 0.f;
}

template <int F>
__global__ __launch_bounds__(256) void k_bn_stats(const float* __restrict__ agg, float* __restrict__ sums) {
    __shared__ float ls[256];
    __shared__ float lq[256];
    int t = threadIdx.x;
    int T = gridDim.x * 256;
    float s = 0.f, q = 0.f;
    for (int idx = blockIdx.x * 256 + t; idx < NN * F; idx += T) {
        float v = agg[idx];
        s += v;
        q += v * v;
    }
    ls[t] = s;
    lq[t] = q;
    __syncthreads();
    if (t < F) {
        float S = 0.f, Q = 0.f;
#pragma unroll
        for (int j = t; j < 256; j += F) { S += ls[j]; Q += lq[j]; }
        atomicAdd(&sums[t], S);
        atomicAdd(&sums[F + t], Q);
    }
}

// ---------------- BN1 apply + ReLU + pre-scale by dinv -> fp16 ----------------
__global__ __launch_bounds__(256) void k_bn_apply1h(const float* __restrict__ h1, const float* __restrict__ sums,
                                                    const float* __restrict__ g, const float* __restrict__ be,
                                                    const float* __restrict__ dinv, __half2* __restrict__ h1h2) {
    int idx = blockIdx.x * 256 + threadIdx.x;
    if (idx >= NN * 32) return;
    int i = idx >> 5;
    int c = idx & 31;
    int f0 = 2 * c, f1 = 2 * c + 1;
    const float invn = 1.0f / (float)NN;
    float mu0 = sums[f0] * invn, mu1 = sums[f1] * invn;
    float sc0 = g[f0] * rsqrtf(sums[64 + f0] * invn - mu0 * mu0 + BN_EPS);
    float sc1 = g[f1] * rsqrtf(sums[64 + f1] * invn - mu1 * mu1 + BN_EPS);
    float2 v = ((const float2*)h1)[idx];
    float dv = dinv[i];
    float r0 = fmaxf((v.x - mu0) * sc0 + be[f0], 0.f) * dv;
    float r1 = fmaxf((v.y - mu1) * sc1 + be[f1], 0.f) * dv;
    h1h2[idx] = __floats2half2_rn(r0, r1);
}

// ---------------- layer-2 aggregation (rows of 32 half2 = 128B) ----------------
__global__ __launch_bounds__(256) void k_gather2(const __half2* __restrict__ h1h2, const int* __restrict__ srcs,
                                                 const int* __restrict__ row_start, const int* __restrict__ deg,
                                                 const float* __restrict__ dinv, float2* __restrict__ aggh2) {
    int lane = threadIdx.x & 63;
    int wid  = threadIdx.x >> 6;
    int d = blockIdx.x * 4 + wid;
    if (d >= NN) return;
    int g = lane >> 5;        // 0..1 edge group
    int c = lane & 31;        // half2 chunk
    int start = row_start[d];
    int cnt   = deg[d];
    float ax = 0.f, ay = 0.f;
    int k = g;
    for (; k + 2 < cnt; k += 4) {
        int s0 = srcs[start + k];
        int s1 = srcs[start + k + 2];
        float2 v0 = __half22float2(h1h2[s0 * 32 + c]);
        float2 v1 = __half22float2(h1h2[s1 * 32 + c]);
        ax += v0.x + v1.x;
        ay += v0.y + v1.y;
    }
    if (k < cnt) {
        int s = srcs[start + k];
        float2 v = __half22float2(h1h2[s * 32 + c]);
        ax += v.x; ay += v.y;
    }
    if (g == 0) {   // self-loop
        float2 v = __half22float2(h1h2[d * 32 + c]);
        ax += v.x; ay += v.y;
    }
    ax += __shfl_xor(ax, 32, 64);
    ay += __shfl_xor(ay, 32, 64);
    if (g == 0) {
        float dd = dinv[d];
        aggh2[d * 32 + c] = make_float2(dd * ax, dd * ay);
    }
}

// ---------------- h2 = aggh @ W2 + b2 ----------------
__global__ __launch_bounds__(256) void k_mm2b(const float* __restrict__ hin, const float* __restrict__ W,
                                              const float* __restrict__ b, float* __restrict__ hout) {
    __shared__ float row[2][64];
    int r = threadIdx.x >> 7;
    int f = threadIdx.x & 127;
    int i = blockIdx.x * 2 + r;
    if (f < 64 && i < NN) row[r][f] = hin[i * 64 + f];
    __syncthreads();
    if (i >= NN) return;
    float acc = b[f];
#pragma unroll
    for (int k = 0; k < 64; ++k) acc += row[r][k] * W[k * 128 + f];
    hout[i * 128 + f] = acc;
}

// ---------------- pooling init ----------------
__global__ __launch_bounds__(256) void k_zero_pool(float* pooled, float* cnt) {
    int i = blockIdx.x * 256 + threadIdx.x;
    if (i < NG * 128) pooled[i] = 0.f;
    if (i < NG) cnt[i] = 0.f;
}

// ---------------- fused BN2 apply + ReLU + segmented pool ----------------
__global__ __launch_bounds__(128) void k_bn_pool2(const float* __restrict__ h2, const float* __restrict__ sums,
                                                  const float* __restrict__ g, const float* __restrict__ be,
                                                  const int* __restrict__ batch,
                                                  float* __restrict__ pooled, float* __restrict__ cnt) {
    int f = threadIdx.x;                 // 0..127
    int i0 = blockIdx.x * 128;
    int iend = min(i0 + 128, NN);
    if (i0 >= NN) return;
    const float invn = 1.0f / (float)NN;
    float mu = sums[f] * invn;
    float sc = g[f] * rsqrtf(sums[128 + f] * invn - mu * mu + BN_EPS);
    float bb = be[f];
    int gp = batch[i0];
    float acc = 0.f;
    int run = 0;
    for (int i = i0; i < iend; ++i) {
        int gg = batch[i];
        if (gg != gp) {
            atomicAdd(&pooled[gp * 128 + f], acc);
            if (f == 0) atomicAdd(&cnt[gp], (float)run);
            acc = 0.f; run = 0; gp = gg;
        }
        float v = h2[(long long)i * 128 + f];
        acc += fmaxf((v - mu) * sc + bb, 0.f);
        run++;
    }
    atomicAdd(&pooled[gp * 128 + f], acc);
    if (f == 0) atomicAdd(&cnt[gp], (float)run);
}

// ---------------- final MLP ----------------
__global__ __launch_bounds__(64) void k_mlp(const float* __restrict__ pooled, const float* __restrict__ cnt,
                                            const float* __restrict__ fW1, const float* __restrict__ fb1,
                                            const float* __restrict__ fW2, const float* __restrict__ fb2,
                                            float* __restrict__ out) {
    int g = blockIdx.x;
    int j = threadIdx.x;
    float inv = 1.0f / fmaxf(cnt[g], 1.0f);
    float acc = fb1[j];
#pragma unroll
    for (int k = 0; k < 128; ++k) acc += (pooled[g * 128 + k] * inv) * fW1[k * 64 + j];
    float hj = fmaxf(acc, 0.f) * fW2[j];
#pragma unroll
    for (int off = 32; off > 0; off >>= 1) hj += __shfl_down(hj, off, 64);
    if (j == 0) out[g] = hj + fb2[0];
}

extern "C" void kernel_launch(void* const* d_in, const int* in_sizes, int n_in,
                              void* d_out, int out_size, void* d_ws, size_t ws_size,
                              hipStream_t stream) {
    const float* x    = (const float*)d_in[0];
    const int*   src  = (const int*)d_in[1];
    const int*   dst  = (const int*)d_in[2];
    const int*   batch= (const int*)d_in[3];
    const float* W1   = (const float*)d_in[4];
    const float* b1   = (const float*)d_in[5];
    const float* g1   = (const float*)d_in[6];
    const float* be1  = (const float*)d_in[7];
    const float* W2   = (const float*)d_in[8];
    const float* b2   = (const float*)d_in[9];
    const float* g2   = (const float*)d_in[10];
    const float* be2  = (const float*)d_in[11];
    const float* fW1  = (const float*)d_in[12];
    const float* fb1  = (const float*)d_in[13];
    const float* fW2  = (const float*)d_in[14];
    const float* fb2  = (const float*)d_in[15];
    float* out = (float*)d_out;

    // ---- workspace layout (same 104.0 MB footprint as R2/R3, lifetime-aliased) ----
    float* ws        = (float*)d_ws;
    int*   deg_i     = (int*)ws;                   // NN
    int*   row_start = deg_i + NN;                 // NN
    float* dinv      = (float*)(row_start + NN);   // NN
    int*   cursor    = (int*)(dinv + NN);          // NN
    int*   bcur      = cursor + NN;                // 256
    float* sums      = (float*)(bcur + 256);       // 256
    float* h1        = sums + 256;                 // NN*64  (live mm1b..bn_apply1h)
    float* agghR     = h1 + NN * 64;               // NN*64  region
    float* h2        = agghR + NN * 64;            // NN*128 region
    // aliases in h1 region:
    __half2* xh2     = (__half2*)h1;               // NN*8 half2 (xcast..gather1; dead before mm1b writes h1)
    float* pooled    = h1;                         // NG*128 (after bn_apply1h)
    float* cntf      = h1 + NG * 128;              // NG
    // aliases in agghR region:
    int*   tmp_scan  = (int*)agghR;                // NN   (scan phase)
    int*   partials  = tmp_scan + NN;              // 512
    unsigned long long* stage = (unsigned long long*)agghR;   // NE (dead after fill2)
    float* aggh      = agghR;                      // NN*64 (written by gather2)
    float2* aggh2    = (float2*)agghR;
    // aliases in h2 region (h2 proper written at mm2b, after these die):
    float*  aggx     = h2;                         // NN*16 fp32 (gather1..mm1b)
    float2* aggx2    = (float2*)h2;
    int*    srcs     = (int*)(h2 + NN * 16);       // NE (fill2..gather2)
    __half2* h1h2    = (__half2*)(h2 + NN * 16 + NE);  // NN*32 half2 (bn_apply1h..gather2)

    // ---- CSR build + norms ----
    k_zero_int<<<(NN + 255) / 256, 256, 0, stream>>>(deg_i, NN);
    k_hist<<<(NE + 255) / 256, 256, 0, stream>>>(dst, deg_i);
    k_scan1<<<NPART, 256, 0, stream>>>(deg_i, tmp_scan, partials);
    k_scan2<<<1, 512, 0, stream>>>(partials);
    k_scan3<<<NPART, 256, 0, stream>>>(deg_i, tmp_scan, partials, row_start, cursor, bcur, dinv);
    k_xcast<<<(NN * 8 + 255) / 256, 256, 0, stream>>>(x, dinv, xh2);
    k_bucket<<<(NE + 256 * EPT - 1) / (256 * EPT), 256, 0, stream>>>(src, dst, bcur, stage);
    k_fill2<<<(NE + 255) / 256, 256, 0, stream>>>(stage, cursor, srcs);

    // ---- layer 1 ----
    k_gather1<<<(NN + 3) / 4, 256, 0, stream>>>(xh2, srcs, row_start, deg_i, dinv, aggx2);
    k_mm1b<<<(NN + 3) / 4, 256, 0, stream>>>(aggx, W1, b1, h1);
    k_zero_sums<<<1, 256, 0, stream>>>(sums);
    k_bn_stats<64><<<256, 256, 0, stream>>>(h1, sums);
    k_bn_apply1h<<<(NN * 32 + 255) / 256, 256, 0, stream>>>(h1, sums, g1, be1, dinv, h1h2);

    // ---- layer 2 ----
    k_gather2<<<(NN + 3) / 4, 256, 0, stream>>>(h1h2, srcs, row_start, deg_i, dinv, aggh2);
    k_mm2b<<<(NN + 1) / 2, 256, 0, stream>>>(aggh, W2, b2, h2);
    k_zero_sums<<<1, 256, 0, stream>>>(sums);
    k_bn_stats<128><<<256, 256, 0, stream>>>(h2, sums);

    // ---- fused BN2+ReLU+pool, then MLP head ----
    k_zero_pool<<<(NG * 128 + 255) / 256, 256, 0, stream>>>(pooled, cntf);
    k_bn_pool2<<<(NN + 127) / 128, 128, 0, stream>>>(h2, sums, g2, be2, batch, pooled, cntf);
    k_mlp<<<NG, 64, 0, stream>>>(pooled, cntf, fW1, fb1, fW2, fb2, out);
}

// Round 5
// 631.660 us; speedup vs baseline: 4.2205x; 1.1856x over previous
//
#include <hip/hip_runtime.h>
#include <hip/hip_fp16.h>

#define NN 100000
#define NE 3200000
#define NG 2000
#define NB 391                 // dst buckets of 256 nodes (391*256 = 100096 >= NN)
#define BKT_SH 8
static constexpr float BN_EPS = 1e-5f;

// ---------------- bucket counting (LDS histogram, ~150k global atomics total) ----------------
__global__ __launch_bounds__(256) void k_zero_int(int* p, int n) {
    int i = blockIdx.x * 256 + threadIdx.x;
    if (i < n) p[i] = 0;
}

__global__ __launch_bounds__(256) void k_bcnt(const int* __restrict__ dst, int* __restrict__ bcnt) {
    __shared__ int lc[NB];
    int t = threadIdx.x;
    for (int i = t; i < NB; i += 256) lc[i] = 0;
    __syncthreads();
    long long e0 = (long long)blockIdx.x * 8192;
    for (int i = 0; i < 32; ++i) {
        long long e = e0 + t + i * 256;
        if (e < NE) atomicAdd(&lc[dst[e] >> BKT_SH], 1);
    }
    __syncthreads();
    for (int i = t; i < NB; i += 256) {
        int c = lc[i];
        if (c) atomicAdd(&bcnt[i], c);
    }
}

// single-block scan of bucket counts -> stage/CSR offsets; init bucket cursors
__global__ __launch_bounds__(512) void k_bscan(const int* __restrict__ bcnt, int* __restrict__ bbase,
                                               int* __restrict__ bcur) {
    __shared__ int buf[512];
    int t = threadIdx.x;
    int v = (t < NB) ? bcnt[t] : 0;
    buf[t] = v;
    __syncthreads();
#pragma unroll
    for (int off = 1; off < 512; off <<= 1) {
        int a = (t >= off) ? buf[t - off] : 0;
        __syncthreads();
        buf[t] += a;
        __syncthreads();
    }
    if (t < NB) {
        int excl = buf[t] - v;
        bbase[t] = excl;
        bcur[t] = excl;
    }
    if (t == NB - 1) bbase[NB] = buf[t];   // == NE
}

// bucket-partition edges into stage (dense contiguous runs per block)
__global__ __launch_bounds__(256) void k_bucket(const int* __restrict__ src, const int* __restrict__ dst,
                                                int* __restrict__ bcur, unsigned long long* __restrict__ stage) {
    __shared__ int cnt[NB];
    __shared__ int base[NB];
    int t = threadIdx.x;
    long long e0 = (long long)blockIdx.x * 8192;
    long long eend = min((long long)NE, e0 + 8192);
    for (int i = t; i < NB; i += 256) cnt[i] = 0;
    __syncthreads();
    for (long long e = e0 + t; e < eend; e += 256)
        atomicAdd(&cnt[dst[e] >> BKT_SH], 1);
    __syncthreads();
    for (int i = t; i < NB; i += 256) {
        int c = cnt[i];
        base[i] = c ? atomicAdd(&bcur[i], c) : 0;
    }
    __syncthreads();
    for (int i = t; i < NB; i += 256) cnt[i] = 0;
    __syncthreads();
    for (long long e = e0 + t; e < eend; e += 256) {
        int d = dst[e];
        int s = src[e];
        int b = d >> BKT_SH;
        int pos = base[b] + atomicAdd(&cnt[b], 1);
        stage[pos] = ((unsigned long long)(unsigned)d << 32) | (unsigned)s;
    }
}

// per-bucket CSR finalize: LDS histogram + scan -> deg/row_start/dinv, LDS-cursor scatter -> srcs
__global__ __launch_bounds__(256) void k_csr(const unsigned long long* __restrict__ stage,
                                             const int* __restrict__ bbase,
                                             int* __restrict__ deg_i, int* __restrict__ row_start,
                                             float* __restrict__ dinv, int* __restrict__ srcs) {
    __shared__ int ldeg[256];
    __shared__ int scn[256];
    __shared__ int lcur[256];
    int t = threadIdx.x;
    int b = blockIdx.x;
    int base = bbase[b];
    int end  = bbase[b + 1];
    ldeg[t] = 0;
    __syncthreads();
    for (int e = base + t; e < end; e += 256)
        atomicAdd(&ldeg[(int)(stage[e] >> 32) & 255], 1);
    __syncthreads();
    int v = ldeg[t];
    scn[t] = v;
    __syncthreads();
#pragma unroll
    for (int off = 1; off < 256; off <<= 1) {
        int a = (t >= off) ? scn[t - off] : 0;
        __syncthreads();
        scn[t] += a;
        __syncthreads();
    }
    int rs = base + scn[t] - v;          // exclusive within bucket + bucket base
    lcur[t] = rs;
    int i = (b << BKT_SH) + t;
    if (i < NN) {
        deg_i[i] = v;
        row_start[i] = rs;
        dinv[i] = rsqrtf((float)(v + 1));   // +1 self-loop
    }
    __syncthreads();
    for (int e = base + t; e < end; e += 256) {
        unsigned long long p = stage[e];
        int d = (int)(p >> 32);
        int s = (int)(p & 0xffffffffu);
        int pos = atomicAdd(&lcur[d & 255], 1);
        srcs[pos] = s;
    }
}

// ---------------- xh = fp16(x * dinv), padded to 16 ----------------
__global__ __launch_bounds__(256) void k_xcast(const float* __restrict__ x, const float* __restrict__ dinv,
                                               __half2* __restrict__ xh2) {
    int idx = blockIdx.x * 256 + threadIdx.x;
    if (idx >= NN * 8) return;
    int i = idx >> 3;
    int c = idx & 7;
    int f0 = 2 * c, f1 = 2 * c + 1;
    float dv = dinv[i];
    float v0 = (f0 < 10) ? x[i * 10 + f0] * dv : 0.f;
    float v1 = (f1 < 10) ? x[i * 10 + f1] * dv : 0.f;
    xh2[idx] = __floats2half2_rn(v0, v1);
}

// ---------------- layer-1 aggregation (rows of 8 half2 = 32B) ----------------
__global__ __launch_bounds__(256) void k_gather1(const __half2* __restrict__ xh2, const int* __restrict__ srcs,
                                                 const int* __restrict__ row_start, const int* __restrict__ deg,
                                                 const float* __restrict__ dinv, float2* __restrict__ aggx2) {
    int lane = threadIdx.x & 63;
    int wid  = threadIdx.x >> 6;
    int d = blockIdx.x * 4 + wid;
    if (d >= NN) return;
    int g = lane >> 3;        // 0..7 edge group
    int c = lane & 7;         // half2 chunk
    int start = row_start[d];
    int cnt   = deg[d];
    float ax = 0.f, ay = 0.f;
    int k = g;
    for (; k + 8 < cnt; k += 16) {
        int s0 = srcs[start + k];
        int s1 = srcs[start + k + 8];
        float2 v0 = __half22float2(xh2[s0 * 8 + c]);
        float2 v1 = __half22float2(xh2[s1 * 8 + c]);
        ax += v0.x + v1.x;
        ay += v0.y + v1.y;
    }
    if (k < cnt) {
        int s = srcs[start + k];
        float2 v = __half22float2(xh2[s * 8 + c]);
        ax += v.x; ay += v.y;
    }
    if (g == 0) {   // self-loop: dinv[d]*x[d] already folded into xh
        float2 v = __half22float2(xh2[d * 8 + c]);
        ax += v.x; ay += v.y;
    }
#pragma unroll
    for (int m = 8; m < 64; m <<= 1) {
        ax += __shfl_xor(ax, m, 64);
        ay += __shfl_xor(ay, m, 64);
    }
    if (g == 0) {
        float dd = dinv[d];
        aggx2[d * 8 + c] = make_float2(dd * ax, dd * ay);
    }
}

// ---------------- h1 = aggx @ W1 + b1 ----------------
__global__ __launch_bounds__(256) void k_mm1b(const float* __restrict__ aggx, const float* __restrict__ W,
                                              const float* __restrict__ b, float* __restrict__ h) {
    int row = blockIdx.x * 4 + (threadIdx.x >> 6);
    int f   = threadIdx.x & 63;
    if (row >= NN) return;
    float acc = b[f];
#pragma unroll
    for (int k = 0; k < 10; ++k) acc += aggx[row * 16 + k] * W[k * 64 + f];
    h[row * 64 + f] = acc;
}

// ---------------- batchnorm stats ----------------
__global__ __launch_bounds__(256) void k_zero_sums(float* sums) {
    if (blockIdx.x == 0) sums[threadIdx.x] = 0.f;
}

template <int F>
__global__ __launch_bounds__(256) void k_bn_stats(const float* __restrict__ agg, float* __restrict__ sums) {
    __shared__ float ls[256];
    __shared__ float lq[256];
    int t = threadIdx.x;
    int T = gridDim.x * 256;
    float s = 0.f, q = 0.f;
    for (int idx = blockIdx.x * 256 + t; idx < NN * F; idx += T) {
        float v = agg[idx];
        s += v;
        q += v * v;
    }
    ls[t] = s;
    lq[t] = q;
    __syncthreads();
    if (t < F) {
        float S = 0.f, Q = 0.f;
#pragma unroll
        for (int j = t; j < 256; j += F) { S += ls[j]; Q += lq[j]; }
        atomicAdd(&sums[t], S);
        atomicAdd(&sums[F + t], Q);
    }
}

// ---------------- BN1 apply + ReLU + pre-scale by dinv -> fp16 ----------------
__global__ __launch_bounds__(256) void k_bn_apply1h(const float* __restrict__ h1, const float* __restrict__ sums,
                                                    const float* __restrict__ g, const float* __restrict__ be,
                                                    const float* __restrict__ dinv, __half2* __restrict__ h1h2) {
    int idx = blockIdx.x * 256 + threadIdx.x;
    if (idx >= NN * 32) return;
    int i = idx >> 5;
    int c = idx & 31;
    int f0 = 2 * c, f1 = 2 * c + 1;
    const float invn = 1.0f / (float)NN;
    float mu0 = sums[f0] * invn, mu1 = sums[f1] * invn;
    float sc0 = g[f0] * rsqrtf(sums[64 + f0] * invn - mu0 * mu0 + BN_EPS);
    float sc1 = g[f1] * rsqrtf(sums[64 + f1] * invn - mu1 * mu1 + BN_EPS);
    float2 v = ((const float2*)h1)[idx];
    float dv = dinv[i];
    float r0 = fmaxf((v.x - mu0) * sc0 + be[f0], 0.f) * dv;
    float r1 = fmaxf((v.y - mu1) * sc1 + be[f1], 0.f) * dv;
    h1h2[idx] = __floats2half2_rn(r0, r1);
}

// ---------------- layer-2 aggregation (rows of 32 half2 = 128B) ----------------
__global__ __launch_bounds__(256) void k_gather2(const __half2* __restrict__ h1h2, const int* __restrict__ srcs,
                                                 const int* __restrict__ row_start, const int* __restrict__ deg,
                                                 const float* __restrict__ dinv, float2* __restrict__ aggh2) {
    int lane = threadIdx.x & 63;
    int wid  = threadIdx.x >> 6;
    int d = blockIdx.x * 4 + wid;
    if (d >= NN) return;
    int g = lane >> 5;        // 0..1 edge group
    int c = lane & 31;        // half2 chunk
    int start = row_start[d];
    int cnt   = deg[d];
    float ax = 0.f, ay = 0.f;
    int k = g;
    for (; k + 2 < cnt; k += 4) {
        int s0 = srcs[start + k];
        int s1 = srcs[start + k + 2];
        float2 v0 = __half22float2(h1h2[s0 * 32 + c]);
        float2 v1 = __half22float2(h1h2[s1 * 32 + c]);
        ax += v0.x + v1.x;
        ay += v0.y + v1.y;
    }
    if (k < cnt) {
        int s = srcs[start + k];
        float2 v = __half22float2(h1h2[s * 32 + c]);
        ax += v.x; ay += v.y;
    }
    if (g == 0) {   // self-loop
        float2 v = __half22float2(h1h2[d * 32 + c]);
        ax += v.x; ay += v.y;
    }
    ax += __shfl_xor(ax, 32, 64);
    ay += __shfl_xor(ay, 32, 64);
    if (g == 0) {
        float dd = dinv[d];
        aggh2[d * 32 + c] = make_float2(dd * ax, dd * ay);
    }
}

// ---------------- h2 = aggh @ W2 + b2 ----------------
__global__ __launch_bounds__(256) void k_mm2b(const float* __restrict__ hin, const float* __restrict__ W,
                                              const float* __restrict__ b, float* __restrict__ hout) {
    __shared__ float row[2][64];
    int r = threadIdx.x >> 7;
    int f = threadIdx.x & 127;
    int i = blockIdx.x * 2 + r;
    if (f < 64 && i < NN) row[r][f] = hin[i * 64 + f];
    __syncthreads();
    if (i >= NN) return;
    float acc = b[f];
#pragma unroll
    for (int k = 0; k < 64; ++k) acc += row[r][k] * W[k * 128 + f];
    hout[i * 128 + f] = acc;
}

// ---------------- pooling init ----------------
__global__ __launch_bounds__(256) void k_zero_pool(float* pooled, float* cnt) {
    int i = blockIdx.x * 256 + threadIdx.x;
    if (i < NG * 128) pooled[i] = 0.f;
    if (i < NG) cnt[i] = 0.f;
}

// ---------------- fused BN2 apply + ReLU + segmented pool ----------------
__global__ __launch_bounds__(128) void k_bn_pool2(const float* __restrict__ h2, const float* __restrict__ sums,
                                                  const float* __restrict__ g, const float* __restrict__ be,
                                                  const int* __restrict__ batch,
                                                  float* __restrict__ pooled, float* __restrict__ cnt) {
    int f = threadIdx.x;                 // 0..127
    int i0 = blockIdx.x * 128;
    int iend = min(i0 + 128, NN);
    if (i0 >= NN) return;
    const float invn = 1.0f / (float)NN;
    float mu = sums[f] * invn;
    float sc = g[f] * rsqrtf(sums[128 + f] * invn - mu * mu + BN_EPS);
    float bb = be[f];
    int gp = batch[i0];
    float acc = 0.f;
    int run = 0;
    for (int i = i0; i < iend; ++i) {
        int gg = batch[i];
        if (gg != gp) {
            atomicAdd(&pooled[gp * 128 + f], acc);
            if (f == 0) atomicAdd(&cnt[gp], (float)run);
            acc = 0.f; run = 0; gp = gg;
        }
        float v = h2[(long long)i * 128 + f];
        acc += fmaxf((v - mu) * sc + bb, 0.f);
        run++;
    }
    atomicAdd(&pooled[gp * 128 + f], acc);
    if (f == 0) atomicAdd(&cnt[gp], (float)run);
}

// ---------------- final MLP ----------------
__global__ __launch_bounds__(64) void k_mlp(const float* __restrict__ pooled, const float* __restrict__ cnt,
                                            const float* __restrict__ fW1, const float* __restrict__ fb1,
                                            const float* __restrict__ fW2, const float* __restrict__ fb2,
                                            float* __restrict__ out) {
    int g = blockIdx.x;
    int j = threadIdx.x;
    float inv = 1.0f / fmaxf(cnt[g], 1.0f);
    float acc = fb1[j];
#pragma unroll
    for (int k = 0; k < 128; ++k) acc += (pooled[g * 128 + k] * inv) * fW1[k * 64 + j];
    float hj = fmaxf(acc, 0.f) * fW2[j];
#pragma unroll
    for (int off = 32; off > 0; off >>= 1) hj += __shfl_down(hj, off, 64);
    if (j == 0) out[g] = hj + fb2[0];
}

extern "C" void kernel_launch(void* const* d_in, const int* in_sizes, int n_in,
                              void* d_out, int out_size, void* d_ws, size_t ws_size,
                              hipStream_t stream) {
    const float* x    = (const float*)d_in[0];
    const int*   src  = (const int*)d_in[1];
    const int*   dst  = (const int*)d_in[2];
    const int*   batch= (const int*)d_in[3];
    const float* W1   = (const float*)d_in[4];
    const float* b1   = (const float*)d_in[5];
    const float* g1   = (const float*)d_in[6];
    const float* be1  = (const float*)d_in[7];
    const float* W2   = (const float*)d_in[8];
    const float* b2   = (const float*)d_in[9];
    const float* g2   = (const float*)d_in[10];
    const float* be2  = (const float*)d_in[11];
    const float* fW1  = (const float*)d_in[12];
    const float* fb1  = (const float*)d_in[13];
    const float* fW2  = (const float*)d_in[14];
    const float* fb2  = (const float*)d_in[15];
    float* out = (float*)d_out;

    // ---- workspace layout (lifetime-aliased; same footprint as R3/R4) ----
    float* ws        = (float*)d_ws;
    int*   deg_i     = (int*)ws;                   // NN
    int*   row_start = deg_i + NN;                 // NN
    float* dinv      = (float*)(row_start + NN);   // NN
    int*   bcnt      = (int*)(dinv + NN);          // NB
    int*   bbase     = bcnt + NB;                  // NB+1
    int*   bcur      = bbase + NB + 1;             // NB
    float* sums      = (float*)(bcur + NB);        // 256
    float* h1        = sums + 256;                 // NN*64  (live mm1b..bn_apply1h)
    float* agghR     = h1 + NN * 64;               // NN*64  region
    float* h2        = agghR + NN * 64;            // NN*128 region
    // aliases in h1 region:
    __half2* xh2     = (__half2*)h1;               // NN*8 half2 (xcast..gather1; dead before mm1b)
    float* pooled    = h1;                         // NG*128 (after bn_apply1h)
    float* cntf      = h1 + NG * 128;              // NG
    // aliases in agghR region:
    unsigned long long* stage = (unsigned long long*)agghR;   // NE (dead after k_csr)
    float* aggh      = agghR;                      // NN*64 (written by gather2)
    float2* aggh2    = (float2*)agghR;
    // aliases in h2 region (h2 proper written at mm2b, after these die):
    float*  aggx     = h2;                         // NN*16 fp32 (gather1..mm1b)
    float2* aggx2    = (float2*)h2;
    int*    srcs     = (int*)(h2 + NN * 16);       // NE (k_csr..gather2)
    __half2* h1h2    = (__half2*)(h2 + NN * 16 + NE);  // NN*32 half2 (bn_apply1h..gather2)

    // ---- CSR build (LDS-local, no O(E) global atomics) ----
    k_zero_int<<<(NB + 255) / 256, 256, 0, stream>>>(bcnt, NB);
    k_bcnt<<<(NE + 8191) / 8192, 256, 0, stream>>>(dst, bcnt);
    k_bscan<<<1, 512, 0, stream>>>(bcnt, bbase, bcur);
    k_bucket<<<(NE + 8191) / 8192, 256, 0, stream>>>(src, dst, bcur, stage);
    k_csr<<<NB, 256, 0, stream>>>(stage, bbase, deg_i, row_start, dinv, srcs);
    k_xcast<<<(NN * 8 + 255) / 256, 256, 0, stream>>>(x, dinv, xh2);

    // ---- layer 1 ----
    k_gather1<<<(NN + 3) / 4, 256, 0, stream>>>(xh2, srcs, row_start, deg_i, dinv, aggx2);
    k_mm1b<<<(NN + 3) / 4, 256, 0, stream>>>(aggx, W1, b1, h1);
    k_zero_sums<<<1, 256, 0, stream>>>(sums);
    k_bn_stats<64><<<256, 256, 0, stream>>>(h1, sums);
    k_bn_apply1h<<<(NN * 32 + 255) / 256, 256, 0, stream>>>(h1, sums, g1, be1, dinv, h1h2);

    // ---- layer 2 ----
    k_gather2<<<(NN + 3) / 4, 256, 0, stream>>>(h1h2, srcs, row_start, deg_i, dinv, aggh2);
    k_mm2b<<<(NN + 1) / 2, 256, 0, stream>>>(aggh, W2, b2, h2);
    k_zero_sums<<<1, 256, 0, stream>>>(sums);
    k_bn_stats<128><<<256, 256, 0, stream>>>(h2, sums);

    // ---- fused BN2+ReLU+pool, then MLP head ----
    k_zero_pool<<<(NG * 128 + 255) / 256, 256, 0, stream>>>(pooled, cntf);
    k_bn_pool2<<<(NN + 127) / 128, 128, 0, stream>>>(h2, sums, g2, be2, batch, pooled, cntf);
    k_mlp<<<NG, 64, 0, stream>>>(pooled, cntf, fW1, fb1, fW2, fb2, out);
}

// Round 6
// 499.382 us; speedup vs baseline: 5.3385x; 1.2649x over previous
//
#include <hip/hip_runtime.h>
#include <hip/hip_fp16.h>

#define NN 100000
#define NE 3200000
#define NG 2000
#define NB 391                 // dst buckets of 256 nodes (391*256 >= NN)
#define BKT_SH 8
static constexpr float BN_EPS = 1e-5f;

// ---------------- init: zero bcnt + BN sum buffers ----------------
__global__ __launch_bounds__(1024) void k_init(int* bcnt, float* s1, float* s2) {
    int t = threadIdx.x;
    if (t < NB) bcnt[t] = 0;
    if (t < 128) s1[t] = 0.f;
    if (t < 256) s2[t] = 0.f;
}

// ---------------- bucket counting (LDS histogram) ----------------
__global__ __launch_bounds__(256) void k_bcnt(const int* __restrict__ dst, int* __restrict__ bcnt) {
    __shared__ int lc[NB];
    int t = threadIdx.x;
    for (int i = t; i < NB; i += 256) lc[i] = 0;
    __syncthreads();
    long long e0 = (long long)blockIdx.x * 8192;
    for (int i = 0; i < 32; ++i) {
        long long e = e0 + t + i * 256;
        if (e < NE) atomicAdd(&lc[dst[e] >> BKT_SH], 1);
    }
    __syncthreads();
    for (int i = t; i < NB; i += 256) {
        int c = lc[i];
        if (c) atomicAdd(&bcnt[i], c);
    }
}

// single-block scan of bucket counts -> stage/CSR offsets; init bucket cursors
__global__ __launch_bounds__(512) void k_bscan(const int* __restrict__ bcnt, int* __restrict__ bbase,
                                               int* __restrict__ bcur) {
    __shared__ int buf[512];
    int t = threadIdx.x;
    int v = (t < NB) ? bcnt[t] : 0;
    buf[t] = v;
    __syncthreads();
#pragma unroll
    for (int off = 1; off < 512; off <<= 1) {
        int a = (t >= off) ? buf[t - off] : 0;
        __syncthreads();
        buf[t] += a;
        __syncthreads();
    }
    if (t < NB) {
        int excl = buf[t] - v;
        bbase[t] = excl;
        bcur[t] = excl;
    }
    if (t == NB - 1) bbase[NB] = buf[t];   // == NE
}

// bucket-partition edges into stage (dense contiguous runs per block)
__global__ __launch_bounds__(256) void k_bucket(const int* __restrict__ src, const int* __restrict__ dst,
                                                int* __restrict__ bcur, unsigned long long* __restrict__ stage) {
    __shared__ int cnt[NB];
    __shared__ int base[NB];
    int t = threadIdx.x;
    long long e0 = (long long)blockIdx.x * 8192;
    long long eend = min((long long)NE, e0 + 8192);
    for (int i = t; i < NB; i += 256) cnt[i] = 0;
    __syncthreads();
    for (long long e = e0 + t; e < eend; e += 256)
        atomicAdd(&cnt[dst[e] >> BKT_SH], 1);
    __syncthreads();
    for (int i = t; i < NB; i += 256) {
        int c = cnt[i];
        base[i] = c ? atomicAdd(&bcur[i], c) : 0;
    }
    __syncthreads();
    for (int i = t; i < NB; i += 256) cnt[i] = 0;
    __syncthreads();
    for (long long e = e0 + t; e < eend; e += 256) {
        int d = dst[e];
        int s = src[e];
        int b = d >> BKT_SH;
        int pos = base[b] + atomicAdd(&cnt[b], 1);
        stage[pos] = ((unsigned long long)(unsigned)d << 32) | (unsigned)s;
    }
}

// per-bucket CSR finalize + fused xh = fp16(x*dinv) cast
__global__ __launch_bounds__(256) void k_csr(const unsigned long long* __restrict__ stage,
                                             const int* __restrict__ bbase, const float* __restrict__ x,
                                             int* __restrict__ deg_i, int* __restrict__ row_start,
                                             float* __restrict__ dinv, int* __restrict__ srcs,
                                             __half2* __restrict__ xh2) {
    __shared__ int ldeg[256];
    __shared__ int scn[256];
    __shared__ int lcur[256];
    int t = threadIdx.x;
    int b = blockIdx.x;
    int base = bbase[b];
    int end  = bbase[b + 1];
    ldeg[t] = 0;
    __syncthreads();
    for (int e = base + t; e < end; e += 256)
        atomicAdd(&ldeg[(int)(stage[e] >> 32) & 255], 1);
    __syncthreads();
    int v = ldeg[t];
    scn[t] = v;
    __syncthreads();
#pragma unroll
    for (int off = 1; off < 256; off <<= 1) {
        int a = (t >= off) ? scn[t - off] : 0;
        __syncthreads();
        scn[t] += a;
        __syncthreads();
    }
    int rs = base + scn[t] - v;
    lcur[t] = rs;
    int i = (b << BKT_SH) + t;
    if (i < NN) {
        deg_i[i] = v;
        row_start[i] = rs;
        float dv = rsqrtf((float)(v + 1));   // +1 self-loop
        dinv[i] = dv;
        float xv[10];
#pragma unroll
        for (int k = 0; k < 10; ++k) xv[k] = x[i * 10 + k] * dv;
#pragma unroll
        for (int c = 0; c < 8; ++c) {
            float a = (2 * c < 10) ? xv[2 * c] : 0.f;
            float bb = (2 * c + 1 < 10) ? xv[2 * c + 1] : 0.f;
            xh2[i * 8 + c] = __floats2half2_rn(a, bb);
        }
    }
    __syncthreads();
    for (int e = base + t; e < end; e += 256) {
        unsigned long long p = stage[e];
        int d = (int)(p >> 32);
        int s = (int)(p & 0xffffffffu);
        int pos = atomicAdd(&lcur[d & 255], 1);
        srcs[pos] = s;
    }
}

// ---------------- layer-1 aggregation: 16B/lane, 32 edge groups x 2 chunks ----------------
__global__ __launch_bounds__(256) void k_gather1(const float4* __restrict__ xh4, const int* __restrict__ srcs,
                                                 const int* __restrict__ row_start, const int* __restrict__ deg,
                                                 const float* __restrict__ dinv, float4* __restrict__ aggx4) {
    int lane = threadIdx.x & 63;
    int wid  = threadIdx.x >> 6;
    int d = blockIdx.x * 4 + wid;
    if (d >= NN) return;
    int c = lane & 1;         // 16B chunk of 32B row
    int g = lane >> 1;        // 0..31 edge group
    int start = row_start[d];
    int cnt   = deg[d];
    float acc[8] = {0.f};
    for (int k = g; k < cnt; k += 32) {
        int s = srcs[start + k];
        float4 r = xh4[s * 2 + c];
        const __half2* p = (const __half2*)&r;
#pragma unroll
        for (int j = 0; j < 4; ++j) {
            float2 u = __half22float2(p[j]);
            acc[2 * j] += u.x; acc[2 * j + 1] += u.y;
        }
    }
    if (g == 0) {   // self-loop (x*dinv already folded)
        float4 r = xh4[d * 2 + c];
        const __half2* p = (const __half2*)&r;
#pragma unroll
        for (int j = 0; j < 4; ++j) {
            float2 u = __half22float2(p[j]);
            acc[2 * j] += u.x; acc[2 * j + 1] += u.y;
        }
    }
#pragma unroll
    for (int m = 2; m < 64; m <<= 1) {
#pragma unroll
        for (int j = 0; j < 8; ++j) acc[j] += __shfl_xor(acc[j], m, 64);
    }
    if (g == 0) {
        float dd = dinv[d];
        float4 o0 = make_float4(dd * acc[0], dd * acc[1], dd * acc[2], dd * acc[3]);
        float4 o1 = make_float4(dd * acc[4], dd * acc[5], dd * acc[6], dd * acc[7]);
        aggx4[d * 4 + c * 2]     = o0;
        aggx4[d * 4 + c * 2 + 1] = o1;
    }
}

// ---------------- h1 = aggx @ W1 + b1 (fp16 out) + fused BN1 stats ----------------
__global__ __launch_bounds__(256) void k_mm1s(const float* __restrict__ aggx, const float* __restrict__ W,
                                              const float* __restrict__ b, __half* __restrict__ h1h,
                                              float* __restrict__ sums1) {
    __shared__ float ls[256];
    __shared__ float lq[256];
    int t = threadIdx.x;
    int rg = t >> 6;
    int f = t & 63;
    float w[10];
#pragma unroll
    for (int k = 0; k < 10; ++k) w[k] = W[k * 64 + f];
    float bf = b[f];
    float s = 0.f, q = 0.f;
    for (int row = blockIdx.x * 4 + rg; row < NN; row += 512 * 4) {
        float acc = bf;
#pragma unroll
        for (int k = 0; k < 10; ++k) acc += aggx[row * 16 + k] * w[k];
        s += acc; q += acc * acc;
        h1h[row * 64 + f] = __float2half(acc);
    }
    ls[t] = s; lq[t] = q;
    __syncthreads();
    if (t < 64) {
        float S = ls[t] + ls[t + 64] + ls[t + 128] + ls[t + 192];
        float Q = lq[t] + lq[t + 64] + lq[t + 128] + lq[t + 192];
        atomicAdd(&sums1[f], S);
        atomicAdd(&sums1[64 + f], Q);
    }
}

// ---------------- BN1 apply + ReLU + pre-scale by dinv -> fp16 ----------------
__global__ __launch_bounds__(256) void k_bn_apply1h(const float4* __restrict__ h1h4, const float* __restrict__ sums1,
                                                    const float* __restrict__ g, const float* __restrict__ be,
                                                    const float* __restrict__ dinv, float4* __restrict__ out4) {
    int idx = blockIdx.x * 256 + threadIdx.x;
    if (idx >= NN * 8) return;
    int i = idx >> 3;
    int c = idx & 7;          // features 8c..8c+7
    const float invn = 1.0f / (float)NN;
    float dv = dinv[i];
    float4 r = h1h4[idx];
    const __half2* p = (const __half2*)&r;
    float4 o;
    __half2* po = (__half2*)&o;
#pragma unroll
    for (int j = 0; j < 4; ++j) {
        int f0 = 8 * c + 2 * j, f1 = f0 + 1;
        float mu0 = sums1[f0] * invn, mu1 = sums1[f1] * invn;
        float sc0 = g[f0] * rsqrtf(sums1[64 + f0] * invn - mu0 * mu0 + BN_EPS);
        float sc1 = g[f1] * rsqrtf(sums1[64 + f1] * invn - mu1 * mu1 + BN_EPS);
        float2 u = __half22float2(p[j]);
        float r0 = fmaxf((u.x - mu0) * sc0 + be[f0], 0.f) * dv;
        float r1 = fmaxf((u.y - mu1) * sc1 + be[f1], 0.f) * dv;
        po[j] = __floats2half2_rn(r0, r1);
    }
    out4[idx] = o;
}

// ---------------- layer-2 aggregation: 16B/lane, 8 edge groups x 8 chunks ----------------
__global__ __launch_bounds__(256) void k_gather2(const float4* __restrict__ h4, const int* __restrict__ srcs,
                                                 const int* __restrict__ row_start, const int* __restrict__ deg,
                                                 const float* __restrict__ dinv, float4* __restrict__ aggh4) {
    int lane = threadIdx.x & 63;
    int wid  = threadIdx.x >> 6;
    int d = blockIdx.x * 4 + wid;
    if (d >= NN) return;
    int c = lane & 7;         // 16B chunk of 128B row
    int g = lane >> 3;        // 0..7 edge group
    int start = row_start[d];
    int cnt   = deg[d];
    float acc[8] = {0.f};
    int k = g;
    for (; k + 8 < cnt; k += 16) {
        int s0 = srcs[start + k];
        int s1 = srcs[start + k + 8];
        float4 r0 = h4[(long long)s0 * 8 + c];
        float4 r1 = h4[(long long)s1 * 8 + c];
        const __half2* p0 = (const __half2*)&r0;
        const __half2* p1 = (const __half2*)&r1;
#pragma unroll
        for (int j = 0; j < 4; ++j) {
            float2 u = __half22float2(p0[j]);
            float2 v = __half22float2(p1[j]);
            acc[2 * j] += u.x + v.x; acc[2 * j + 1] += u.y + v.y;
        }
    }
    if (k < cnt) {
        int s = srcs[start + k];
        float4 r = h4[(long long)s * 8 + c];
        const __half2* p = (const __half2*)&r;
#pragma unroll
        for (int j = 0; j < 4; ++j) {
            float2 u = __half22float2(p[j]);
            acc[2 * j] += u.x; acc[2 * j + 1] += u.y;
        }
    }
    if (g == 0) {   // self-loop
        float4 r = h4[(long long)d * 8 + c];
        const __half2* p = (const __half2*)&r;
#pragma unroll
        for (int j = 0; j < 4; ++j) {
            float2 u = __half22float2(p[j]);
            acc[2 * j] += u.x; acc[2 * j + 1] += u.y;
        }
    }
#pragma unroll
    for (int m = 8; m < 64; m <<= 1) {
#pragma unroll
        for (int j = 0; j < 8; ++j) acc[j] += __shfl_xor(acc[j], m, 64);
    }
    if (g == 0) {
        float dd = dinv[d];
        float4 o0 = make_float4(dd * acc[0], dd * acc[1], dd * acc[2], dd * acc[3]);
        float4 o1 = make_float4(dd * acc[4], dd * acc[5], dd * acc[6], dd * acc[7]);
        aggh4[d * 16 + c * 2]     = o0;
        aggh4[d * 16 + c * 2 + 1] = o1;
    }
}

// ---------------- h2 = aggh @ W2 + b2 + fused BN2 stats + zero pooled ----------------
__global__ __launch_bounds__(256) void k_mm2s(const float* __restrict__ aggh, const float* __restrict__ W,
                                              const float* __restrict__ b, float* __restrict__ h2,
                                              float* __restrict__ sums2, float* __restrict__ pooled) {
    int t = threadIdx.x;
    // zero pooled + cnt (contiguous NG*128 + NG floats)
    for (int i = blockIdx.x * 256 + t; i < NG * 128 + NG; i += 512 * 256) pooled[i] = 0.f;
    __shared__ float rowbuf[2][64];
    __shared__ float ls[256];
    __shared__ float lq[256];
    int rg = t >> 7;
    int f = t & 127;
    float w[64];
#pragma unroll
    for (int k = 0; k < 64; ++k) w[k] = W[k * 128 + f];
    float bf = b[f];
    float s = 0.f, q = 0.f;
    for (int r0 = blockIdx.x * 2; r0 < NN; r0 += 1024) {
        __syncthreads();
        if (t < 128) {
            int rr = t >> 6, k = t & 63;
            int row = r0 + rr;
            rowbuf[rr][k] = (row < NN) ? aggh[row * 64 + k] : 0.f;
        }
        __syncthreads();
        int row = r0 + rg;
        if (row < NN) {
            float acc = bf;
#pragma unroll
            for (int k = 0; k < 64; ++k) acc += rowbuf[rg][k] * w[k];
            h2[(long long)row * 128 + f] = acc;
            s += acc; q += acc * acc;
        }
    }
    ls[t] = s; lq[t] = q;
    __syncthreads();
    if (t < 128) {
        float S = ls[t] + ls[t + 128];
        float Q = lq[t] + lq[t + 128];
        atomicAdd(&sums2[f], S);
        atomicAdd(&sums2[128 + f], Q);
    }
}

// ---------------- fused BN2 apply + ReLU + segmented pool ----------------
__global__ __launch_bounds__(128) void k_bn_pool2(const float* __restrict__ h2, const float* __restrict__ sums2,
                                                  const float* __restrict__ g, const float* __restrict__ be,
                                                  const int* __restrict__ batch,
                                                  float* __restrict__ pooled, float* __restrict__ cnt) {
    int f = threadIdx.x;                 // 0..127
    int i0 = blockIdx.x * 128;
    int iend = min(i0 + 128, NN);
    if (i0 >= NN) return;
    const float invn = 1.0f / (float)NN;
    float mu = sums2[f] * invn;
    float sc = g[f] * rsqrtf(sums2[128 + f] * invn - mu * mu + BN_EPS);
    float bb = be[f];
    int gp = batch[i0];
    float acc = 0.f;
    int run = 0;
    for (int i = i0; i < iend; ++i) {
        int gg = batch[i];
        if (gg != gp) {
            atomicAdd(&pooled[gp * 128 + f], acc);
            if (f == 0) atomicAdd(&cnt[gp], (float)run);
            acc = 0.f; run = 0; gp = gg;
        }
        float v = h2[(long long)i * 128 + f];
        acc += fmaxf((v - mu) * sc + bb, 0.f);
        run++;
    }
    atomicAdd(&pooled[gp * 128 + f], acc);
    if (f == 0) atomicAdd(&cnt[gp], (float)run);
}

// ---------------- final MLP ----------------
__global__ __launch_bounds__(64) void k_mlp(const float* __restrict__ pooled, const float* __restrict__ cnt,
                                            const float* __restrict__ fW1, const float* __restrict__ fb1,
                                            const float* __restrict__ fW2, const float* __restrict__ fb2,
                                            float* __restrict__ out) {
    int g = blockIdx.x;
    int j = threadIdx.x;
    float inv = 1.0f / fmaxf(cnt[g], 1.0f);
    float acc = fb1[j];
#pragma unroll
    for (int k = 0; k < 128; ++k) acc += (pooled[g * 128 + k] * inv) * fW1[k * 64 + j];
    float hj = fmaxf(acc, 0.f) * fW2[j];
#pragma unroll
    for (int off = 32; off > 0; off >>= 1) hj += __shfl_down(hj, off, 64);
    if (j == 0) out[g] = hj + fb2[0];
}

extern "C" void kernel_launch(void* const* d_in, const int* in_sizes, int n_in,
                              void* d_out, int out_size, void* d_ws, size_t ws_size,
                              hipStream_t stream) {
    const float* x    = (const float*)d_in[0];
    const int*   src  = (const int*)d_in[1];
    const int*   dst  = (const int*)d_in[2];
    const int*   batch= (const int*)d_in[3];
    const float* W1   = (const float*)d_in[4];
    const float* b1   = (const float*)d_in[5];
    const float* g1   = (const float*)d_in[6];
    const float* be1  = (const float*)d_in[7];
    const float* W2   = (const float*)d_in[8];
    const float* b2   = (const float*)d_in[9];
    const float* g2   = (const float*)d_in[10];
    const float* be2  = (const float*)d_in[11];
    const float* fW1  = (const float*)d_in[12];
    const float* fb1  = (const float*)d_in[13];
    const float* fW2  = (const float*)d_in[14];
    const float* fb2  = (const float*)d_in[15];
    float* out = (float*)d_out;

    // ---- workspace layout (lifetime-aliased; ~103.6 MB) ----
    float* ws        = (float*)d_ws;
    int*   deg_i     = (int*)ws;                   // NN
    int*   row_start = deg_i + NN;                 // NN
    float* dinv      = (float*)(row_start + NN);   // NN
    int*   bcnt      = (int*)(dinv + NN);          // NB
    int*   bbase     = bcnt + NB;                  // NB+1
    int*   bcur      = bbase + NB + 1;             // NB
    float* sums1     = (float*)(bcur + NB);        // 128
    float* sums2     = sums1 + 128;                // 256
    float* h1R       = sums2 + 256;                // NN*64 floats region
    float* agghR     = h1R + NN * 64;              // NN*64 floats region
    float* h2R       = agghR + NN * 64;            // NN*128 floats region
    // h1R aliases: xh2 (csr..gather1), h1h (mm1s..bn_apply1h), pooled+cnt (mm2s..mlp)
    __half2* xh2     = (__half2*)h1R;              // NN*8 half2 (3.2 MB)
    __half*  h1h     = (__half*)h1R;               // NN*64 half (12.8 MB)
    float*   pooled  = h1R;                        // NG*128
    float*   cntf    = h1R + NG * 128;             // NG (contiguous with pooled)
    // agghR aliases: stage (bucket..csr), aggh (gather2..mm2s)
    unsigned long long* stage = (unsigned long long*)agghR;   // NE * 8B
    float*   aggh    = agghR;                      // NN*64 floats
    // h2R aliases: aggx (gather1..mm1s), srcs (csr..gather2), h1h2 (bn_apply1h..gather2); then h2 (mm2s..bn_pool2)
    float*   aggx    = h2R;                        // NN*16 floats
    int*     srcs    = (int*)(h2R + NN * 16);      // NE ints
    __half2* h1h2    = (__half2*)(h2R + NN * 16 + NE);  // NN*32 half2
    float*   h2      = h2R;                        // NN*128 floats

    // ---- CSR build ----
    k_init<<<1, 1024, 0, stream>>>(bcnt, sums1, sums2);
    k_bcnt<<<(NE + 8191) / 8192, 256, 0, stream>>>(dst, bcnt);
    k_bscan<<<1, 512, 0, stream>>>(bcnt, bbase, bcur);
    k_bucket<<<(NE + 8191) / 8192, 256, 0, stream>>>(src, dst, bcur, stage);
    k_csr<<<NB, 256, 0, stream>>>(stage, bbase, x, deg_i, row_start, dinv, srcs, xh2);

    // ---- layer 1 ----
    k_gather1<<<(NN + 3) / 4, 256, 0, stream>>>((const float4*)xh2, srcs, row_start, deg_i, dinv, (float4*)aggx);
    k_mm1s<<<512, 256, 0, stream>>>(aggx, W1, b1, h1h, sums1);
    k_bn_apply1h<<<(NN * 8 + 255) / 256, 256, 0, stream>>>((const float4*)h1h, sums1, g1, be1, dinv, (float4*)h1h2);

    // ---- layer 2 ----
    k_gather2<<<(NN + 3) / 4, 256, 0, stream>>>((const float4*)h1h2, srcs, row_start, deg_i, dinv, (float4*)aggh);
    k_mm2s<<<512, 256, 0, stream>>>(aggh, W2, b2, h2, sums2, pooled);

    // ---- fused BN2+ReLU+pool, then MLP head ----
    k_bn_pool2<<<(NN + 127) / 128, 128, 0, stream>>>(h2, sums2, g2, be2, batch, pooled, cntf);
    k_mlp<<<NG, 64, 0, stream>>>(pooled, cntf, fW1, fb1, fW2, fb2, out);
}

// Round 7
// 433.161 us; speedup vs baseline: 6.1546x; 1.1529x over previous
//
#include <hip/hip_runtime.h>
#include <hip/hip_fp16.h>

#define NN 100000
#define NE 3200000
#define NG 2000
#define NB 391                 // dst buckets of 256 nodes (391*256 >= NN)
#define BKT_SH 8
static constexpr float BN_EPS = 1e-5f;

typedef _Float16 f16x8 __attribute__((ext_vector_type(8)));
typedef float    f32x4 __attribute__((ext_vector_type(4)));

// ---------------- init: zero bcnt + BN sum buffers ----------------
__global__ __launch_bounds__(1024) void k_init(int* bcnt, float* s1, float* s2) {
    int t = threadIdx.x;
    if (t < NB) bcnt[t] = 0;
    if (t < 128) s1[t] = 0.f;
    if (t < 256) s2[t] = 0.f;
}

// ---------------- bucket counting (LDS histogram) ----------------
__global__ __launch_bounds__(256) void k_bcnt(const int* __restrict__ dst, int* __restrict__ bcnt) {
    __shared__ int lc[NB];
    int t = threadIdx.x;
    for (int i = t; i < NB; i += 256) lc[i] = 0;
    __syncthreads();
    long long e0 = (long long)blockIdx.x * 8192;
    for (int i = 0; i < 32; ++i) {
        long long e = e0 + t + i * 256;
        if (e < NE) atomicAdd(&lc[dst[e] >> BKT_SH], 1);
    }
    __syncthreads();
    for (int i = t; i < NB; i += 256) {
        int c = lc[i];
        if (c) atomicAdd(&bcnt[i], c);
    }
}

// single-block scan of bucket counts -> stage/CSR offsets; init bucket cursors
__global__ __launch_bounds__(512) void k_bscan(const int* __restrict__ bcnt, int* __restrict__ bbase,
                                               int* __restrict__ bcur) {
    __shared__ int buf[512];
    int t = threadIdx.x;
    int v = (t < NB) ? bcnt[t] : 0;
    buf[t] = v;
    __syncthreads();
#pragma unroll
    for (int off = 1; off < 512; off <<= 1) {
        int a = (t >= off) ? buf[t - off] : 0;
        __syncthreads();
        buf[t] += a;
        __syncthreads();
    }
    if (t < NB) {
        int excl = buf[t] - v;
        bbase[t] = excl;
        bcur[t] = excl;
    }
    if (t == NB - 1) bbase[NB] = buf[t];   // == NE
}

// bucket-partition edges into stage (dense contiguous runs per block)
__global__ __launch_bounds__(256) void k_bucket(const int* __restrict__ src, const int* __restrict__ dst,
                                                int* __restrict__ bcur, unsigned long long* __restrict__ stage) {
    __shared__ int cnt[NB];
    __shared__ int base[NB];
    int t = threadIdx.x;
    long long e0 = (long long)blockIdx.x * 8192;
    long long eend = min((long long)NE, e0 + 8192);
    for (int i = t; i < NB; i += 256) cnt[i] = 0;
    __syncthreads();
    for (long long e = e0 + t; e < eend; e += 256)
        atomicAdd(&cnt[dst[e] >> BKT_SH], 1);
    __syncthreads();
    for (int i = t; i < NB; i += 256) {
        int c = cnt[i];
        base[i] = c ? atomicAdd(&bcur[i], c) : 0;
    }
    __syncthreads();
    for (int i = t; i < NB; i += 256) cnt[i] = 0;
    __syncthreads();
    for (long long e = e0 + t; e < eend; e += 256) {
        int d = dst[e];
        int s = src[e];
        int b = d >> BKT_SH;
        int pos = base[b] + atomicAdd(&cnt[b], 1);
        stage[pos] = ((unsigned long long)(unsigned)d << 32) | (unsigned)s;
    }
}

// per-bucket CSR finalize + fused xh = fp16(x*dinv) cast
__global__ __launch_bounds__(256) void k_csr(const unsigned long long* __restrict__ stage,
                                             const int* __restrict__ bbase, const float* __restrict__ x,
                                             int* __restrict__ deg_i, int* __restrict__ row_start,
                                             float* __restrict__ dinv, int* __restrict__ srcs,
                                             __half2* __restrict__ xh2) {
    __shared__ int ldeg[256];
    __shared__ int scn[256];
    __shared__ int lcur[256];
    int t = threadIdx.x;
    int b = blockIdx.x;
    int base = bbase[b];
    int end  = bbase[b + 1];
    ldeg[t] = 0;
    __syncthreads();
    for (int e = base + t; e < end; e += 256)
        atomicAdd(&ldeg[(int)(stage[e] >> 32) & 255], 1);
    __syncthreads();
    int v = ldeg[t];
    scn[t] = v;
    __syncthreads();
#pragma unroll
    for (int off = 1; off < 256; off <<= 1) {
        int a = (t >= off) ? scn[t - off] : 0;
        __syncthreads();
        scn[t] += a;
        __syncthreads();
    }
    int rs = base + scn[t] - v;
    lcur[t] = rs;
    int i = (b << BKT_SH) + t;
    if (i < NN) {
        deg_i[i] = v;
        row_start[i] = rs;
        float dv = rsqrtf((float)(v + 1));   // +1 self-loop
        dinv[i] = dv;
        float xv[10];
#pragma unroll
        for (int k = 0; k < 10; ++k) xv[k] = x[i * 10 + k] * dv;
#pragma unroll
        for (int c = 0; c < 8; ++c) {
            float a = (2 * c < 10) ? xv[2 * c] : 0.f;
            float bb = (2 * c + 1 < 10) ? xv[2 * c + 1] : 0.f;
            xh2[i * 8 + c] = __floats2half2_rn(a, bb);
        }
    }
    __syncthreads();
    for (int e = base + t; e < end; e += 256) {
        unsigned long long p = stage[e];
        int d = (int)(p >> 32);
        int s = (int)(p & 0xffffffffu);
        int pos = atomicAdd(&lcur[d & 255], 1);
        srcs[pos] = s;
    }
}

// ---------------- layer-1 aggregation: 16B/lane, 32 edge groups x 2 chunks ----------------
__global__ __launch_bounds__(256) void k_gather1(const float4* __restrict__ xh4, const int* __restrict__ srcs,
                                                 const int* __restrict__ row_start, const int* __restrict__ deg,
                                                 const float* __restrict__ dinv, float4* __restrict__ aggx4) {
    int lane = threadIdx.x & 63;
    int wid  = threadIdx.x >> 6;
    int d = blockIdx.x * 4 + wid;
    if (d >= NN) return;
    int c = lane & 1;         // 16B chunk of 32B row
    int g = lane >> 1;        // 0..31 edge group
    int start = row_start[d];
    int cnt   = deg[d];
    float acc[8] = {0.f};
    for (int k = g; k < cnt; k += 32) {
        int s = srcs[start + k];
        float4 r = xh4[s * 2 + c];
        const __half2* p = (const __half2*)&r;
#pragma unroll
        for (int j = 0; j < 4; ++j) {
            float2 u = __half22float2(p[j]);
            acc[2 * j] += u.x; acc[2 * j + 1] += u.y;
        }
    }
    if (g == 0) {   // self-loop (x*dinv already folded)
        float4 r = xh4[d * 2 + c];
        const __half2* p = (const __half2*)&r;
#pragma unroll
        for (int j = 0; j < 4; ++j) {
            float2 u = __half22float2(p[j]);
            acc[2 * j] += u.x; acc[2 * j + 1] += u.y;
        }
    }
#pragma unroll
    for (int m = 2; m < 64; m <<= 1) {
#pragma unroll
        for (int j = 0; j < 8; ++j) acc[j] += __shfl_xor(acc[j], m, 64);
    }
    if (g == 0) {
        float dd = dinv[d];
        float4 o0 = make_float4(dd * acc[0], dd * acc[1], dd * acc[2], dd * acc[3]);
        float4 o1 = make_float4(dd * acc[4], dd * acc[5], dd * acc[6], dd * acc[7]);
        aggx4[d * 4 + c * 2]     = o0;
        aggx4[d * 4 + c * 2 + 1] = o1;
    }
}

// ---------------- h1 = aggx @ W1 + b1 (fp16 out) + fused BN1 stats ----------------
__global__ __launch_bounds__(256) void k_mm1s(const float* __restrict__ aggx, const float* __restrict__ W,
                                              const float* __restrict__ b, __half* __restrict__ h1h,
                                              float* __restrict__ sums1) {
    __shared__ float ls[256];
    __shared__ float lq[256];
    int t = threadIdx.x;
    int rg = t >> 6;
    int f = t & 63;
    float w[10];
#pragma unroll
    for (int k = 0; k < 10; ++k) w[k] = W[k * 64 + f];
    float bf = b[f];
    float s = 0.f, q = 0.f;
    for (int row = blockIdx.x * 4 + rg; row < NN; row += 512 * 4) {
        float acc = bf;
#pragma unroll
        for (int k = 0; k < 10; ++k) acc += aggx[row * 16 + k] * w[k];
        s += acc; q += acc * acc;
        h1h[row * 64 + f] = __float2half(acc);
    }
    ls[t] = s; lq[t] = q;
    __syncthreads();
    if (t < 64) {
        float S = ls[t] + ls[t + 64] + ls[t + 128] + ls[t + 192];
        float Q = lq[t] + lq[t + 64] + lq[t + 128] + lq[t + 192];
        atomicAdd(&sums1[f], S);
        atomicAdd(&sums1[64 + f], Q);
    }
}

// ---------------- BN1 apply + ReLU + pre-scale by dinv -> fp16 ----------------
__global__ __launch_bounds__(256) void k_bn_apply1h(const float4* __restrict__ h1h4, const float* __restrict__ sums1,
                                                    const float* __restrict__ g, const float* __restrict__ be,
                                                    const float* __restrict__ dinv, float4* __restrict__ out4) {
    int idx = blockIdx.x * 256 + threadIdx.x;
    if (idx >= NN * 8) return;
    int i = idx >> 3;
    int c = idx & 7;          // features 8c..8c+7
    const float invn = 1.0f / (float)NN;
    float dv = dinv[i];
    float4 r = h1h4[idx];
    const __half2* p = (const __half2*)&r;
    float4 o;
    __half2* po = (__half2*)&o;
#pragma unroll
    for (int j = 0; j < 4; ++j) {
        int f0 = 8 * c + 2 * j, f1 = f0 + 1;
        float mu0 = sums1[f0] * invn, mu1 = sums1[f1] * invn;
        float sc0 = g[f0] * rsqrtf(sums1[64 + f0] * invn - mu0 * mu0 + BN_EPS);
        float sc1 = g[f1] * rsqrtf(sums1[64 + f1] * invn - mu1 * mu1 + BN_EPS);
        float2 u = __half22float2(p[j]);
        float r0 = fmaxf((u.x - mu0) * sc0 + be[f0], 0.f) * dv;
        float r1 = fmaxf((u.y - mu1) * sc1 + be[f1], 0.f) * dv;
        po[j] = __floats2half2_rn(r0, r1);
    }
    out4[idx] = o;
}

// ---------------- layer-2 aggregation: 16B/lane, 8 edge groups x 8 chunks; fp16 out ----------------
__global__ __launch_bounds__(256) void k_gather2(const float4* __restrict__ h4, const int* __restrict__ srcs,
                                                 const int* __restrict__ row_start, const int* __restrict__ deg,
                                                 const float* __restrict__ dinv, float4* __restrict__ aggh4) {
    int lane = threadIdx.x & 63;
    int wid  = threadIdx.x >> 6;
    int d = blockIdx.x * 4 + wid;
    if (d >= NN) return;
    int c = lane & 7;         // 16B chunk of 128B row
    int g = lane >> 3;        // 0..7 edge group
    int start = row_start[d];
    int cnt   = deg[d];
    float acc[8] = {0.f};
    int k = g;
    for (; k + 8 < cnt; k += 16) {
        int s0 = srcs[start + k];
        int s1 = srcs[start + k + 8];
        float4 r0 = h4[(long long)s0 * 8 + c];
        float4 r1 = h4[(long long)s1 * 8 + c];
        const __half2* p0 = (const __half2*)&r0;
        const __half2* p1 = (const __half2*)&r1;
#pragma unroll
        for (int j = 0; j < 4; ++j) {
            float2 u = __half22float2(p0[j]);
            float2 v = __half22float2(p1[j]);
            acc[2 * j] += u.x + v.x; acc[2 * j + 1] += u.y + v.y;
        }
    }
    if (k < cnt) {
        int s = srcs[start + k];
        float4 r = h4[(long long)s * 8 + c];
        const __half2* p = (const __half2*)&r;
#pragma unroll
        for (int j = 0; j < 4; ++j) {
            float2 u = __half22float2(p[j]);
            acc[2 * j] += u.x; acc[2 * j + 1] += u.y;
        }
    }
    if (g == 0) {   // self-loop
        float4 r = h4[(long long)d * 8 + c];
        const __half2* p = (const __half2*)&r;
#pragma unroll
        for (int j = 0; j < 4; ++j) {
            float2 u = __half22float2(p[j]);
            acc[2 * j] += u.x; acc[2 * j + 1] += u.y;
        }
    }
#pragma unroll
    for (int m = 8; m < 64; m <<= 1) {
#pragma unroll
        for (int j = 0; j < 8; ++j) acc[j] += __shfl_xor(acc[j], m, 64);
    }
    if (g == 0) {
        float dd = dinv[d];
        __half2 o[4];
#pragma unroll
        for (int j = 0; j < 4; ++j)
            o[j] = __floats2half2_rn(dd * acc[2 * j], dd * acc[2 * j + 1]);
        aggh4[d * 8 + c] = *(const float4*)o;   // 8 fp16 = 16B
    }
}

// ---------------- h2 = aggh @ W2 + b2 via MFMA 16x16x32 f16; fused BN2 stats + pooled zero ----------------
__global__ __launch_bounds__(256) void k_mm2m(const __half* __restrict__ aggh, const float* __restrict__ W,
                                              const float* __restrict__ b, __half* __restrict__ h2,
                                              float* __restrict__ sums2, float* __restrict__ pooled) {
    int t = threadIdx.x;
    // zero pooled + cnt (contiguous NG*128 + NG floats); grid = 128 blocks
    for (int i = blockIdx.x * 256 + t; i < NG * 128 + NG; i += 128 * 256) pooled[i] = 0.f;

    __shared__ _Float16 w2h[64 * 128];
    for (int i = t; i < 64 * 128; i += 256) w2h[i] = (_Float16)W[i];
    __syncthreads();

    int lane = t & 63;
    int wid  = t >> 6;
    int quad = lane >> 4;
    int n16  = lane & 15;

    // B-fragments: B[k=kk*32+quad*8+j][n=nt*16+n16]
    f16x8 bfr[8][2];
#pragma unroll
    for (int nt = 0; nt < 8; ++nt)
#pragma unroll
        for (int kk = 0; kk < 2; ++kk)
#pragma unroll
            for (int j = 0; j < 8; ++j)
                bfr[nt][kk][j] = w2h[(kk * 32 + quad * 8 + j) * 128 + nt * 16 + n16];
    float bcol[8];
#pragma unroll
    for (int nt = 0; nt < 8; ++nt) bcol[nt] = b[nt * 16 + n16];

    const f16x8* a8 = (const f16x8*)aggh;
    float s[8] = {0.f}, q[8] = {0.f};

    for (int rt = blockIdx.x * 4 + wid; rt < NN / 16; rt += 128 * 4) {
        int arow = rt * 16 + n16;             // A m-index = lane&15
        f16x8 a0 = a8[arow * 8 + quad];       // k = quad*8..quad*8+7
        f16x8 a1 = a8[arow * 8 + 4 + quad];   // k = 32+quad*8..
#pragma unroll
        for (int nt = 0; nt < 8; ++nt) {
            f32x4 c = {0.f, 0.f, 0.f, 0.f};
            c = __builtin_amdgcn_mfma_f32_16x16x32_f16(a0, bfr[nt][0], c, 0, 0, 0);
            c = __builtin_amdgcn_mfma_f32_16x16x32_f16(a1, bfr[nt][1], c, 0, 0, 0);
            float bb = bcol[nt];
#pragma unroll
            for (int reg = 0; reg < 4; ++reg) {
                float v = c[reg] + bb;
                s[nt] += v; q[nt] += v * v;
                int row = rt * 16 + quad * 4 + reg;   // C row = quad*4+reg
                h2[(long long)row * 128 + nt * 16 + n16] = __float2half(v);
            }
        }
    }
    // reduce stats: sum across quads (same column), then block LDS reduce
#pragma unroll
    for (int nt = 0; nt < 8; ++nt) {
        s[nt] += __shfl_xor(s[nt], 16, 64); s[nt] += __shfl_xor(s[nt], 32, 64);
        q[nt] += __shfl_xor(q[nt], 16, 64); q[nt] += __shfl_xor(q[nt], 32, 64);
    }
    __shared__ float lsS[4][128];
    __shared__ float lsQ[4][128];
    if (lane < 16) {
#pragma unroll
        for (int nt = 0; nt < 8; ++nt) {
            lsS[wid][nt * 16 + lane] = s[nt];
            lsQ[wid][nt * 16 + lane] = q[nt];
        }
    }
    __syncthreads();
    if (t < 128) {
        float S = lsS[0][t] + lsS[1][t] + lsS[2][t] + lsS[3][t];
        float Q = lsQ[0][t] + lsQ[1][t] + lsQ[2][t] + lsQ[3][t];
        atomicAdd(&sums2[t], S);
        atomicAdd(&sums2[128 + t], Q);
    }
}

// ---------------- fused BN2 apply + ReLU + segmented pool (fp16 h2) ----------------
__global__ __launch_bounds__(128) void k_bn_pool2(const __half* __restrict__ h2, const float* __restrict__ sums2,
                                                  const float* __restrict__ g, const float* __restrict__ be,
                                                  const int* __restrict__ batch,
                                                  float* __restrict__ pooled, float* __restrict__ cnt) {
    int f = threadIdx.x;                 // 0..127
    int i0 = blockIdx.x * 128;
    int iend = min(i0 + 128, NN);
    if (i0 >= NN) return;
    const float invn = 1.0f / (float)NN;
    float mu = sums2[f] * invn;
    float sc = g[f] * rsqrtf(sums2[128 + f] * invn - mu * mu + BN_EPS);
    float bb = be[f];
    int gp = batch[i0];
    float acc = 0.f;
    int run = 0;
    for (int i = i0; i < iend; ++i) {
        int gg = batch[i];
        if (gg != gp) {
            atomicAdd(&pooled[gp * 128 + f], acc);
            if (f == 0) atomicAdd(&cnt[gp], (float)run);
            acc = 0.f; run = 0; gp = gg;
        }
        float v = __half2float(h2[(long long)i * 128 + f]);
        acc += fmaxf((v - mu) * sc + bb, 0.f);
        run++;
    }
    atomicAdd(&pooled[gp * 128 + f], acc);
    if (f == 0) atomicAdd(&cnt[gp], (float)run);
}

// ---------------- final MLP ----------------
__global__ __launch_bounds__(64) void k_mlp(const float* __restrict__ pooled, const float* __restrict__ cnt,
                                            const float* __restrict__ fW1, const float* __restrict__ fb1,
                                            const float* __restrict__ fW2, const float* __restrict__ fb2,
                                            float* __restrict__ out) {
    int g = blockIdx.x;
    int j = threadIdx.x;
    float inv = 1.0f / fmaxf(cnt[g], 1.0f);
    float acc = fb1[j];
#pragma unroll
    for (int k = 0; k < 128; ++k) acc += (pooled[g * 128 + k] * inv) * fW1[k * 64 + j];
    float hj = fmaxf(acc, 0.f) * fW2[j];
#pragma unroll
    for (int off = 32; off > 0; off >>= 1) hj += __shfl_down(hj, off, 64);
    if (j == 0) out[g] = hj + fb2[0];
}

extern "C" void kernel_launch(void* const* d_in, const int* in_sizes, int n_in,
                              void* d_out, int out_size, void* d_ws, size_t ws_size,
                              hipStream_t stream) {
    const float* x    = (const float*)d_in[0];
    const int*   src  = (const int*)d_in[1];
    const int*   dst  = (const int*)d_in[2];
    const int*   batch= (const int*)d_in[3];
    const float* W1   = (const float*)d_in[4];
    const float* b1   = (const float*)d_in[5];
    const float* g1   = (const float*)d_in[6];
    const float* be1  = (const float*)d_in[7];
    const float* W2   = (const float*)d_in[8];
    const float* b2   = (const float*)d_in[9];
    const float* g2   = (const float*)d_in[10];
    const float* be2  = (const float*)d_in[11];
    const float* fW1  = (const float*)d_in[12];
    const float* fb1  = (const float*)d_in[13];
    const float* fW2  = (const float*)d_in[14];
    const float* fb2  = (const float*)d_in[15];
    float* out = (float*)d_out;

    // ---- workspace layout (lifetime-aliased; ~103.6 MB) ----
    float* ws        = (float*)d_ws;
    int*   deg_i     = (int*)ws;                   // NN
    int*   row_start = deg_i + NN;                 // NN
    float* dinv      = (float*)(row_start + NN);   // NN
    int*   bcnt      = (int*)(dinv + NN);          // NB
    int*   bbase     = bcnt + NB;                  // NB+1
    int*   bcur      = bbase + NB + 1;             // NB
    float* sums1     = (float*)(bcur + NB);        // 128
    float* sums2     = sums1 + 128;                // 256
    float* h1R       = sums2 + 256;                // NN*64 floats region
    float* agghR     = h1R + NN * 64;              // NN*64 floats region
    float* h2R       = agghR + NN * 64;            // NN*128 floats region
    // h1R aliases: xh2 (csr..gather1), h1h (mm1s..bn_apply1h), pooled+cnt (mm2m..mlp)
    __half2* xh2     = (__half2*)h1R;              // NN*8 half2
    __half*  h1h     = (__half*)h1R;               // NN*64 half
    float*   pooled  = h1R;                        // NG*128
    float*   cntf    = h1R + NG * 128;             // NG
    // agghR aliases: stage (bucket..csr), aggh fp16 (gather2..mm2m)
    unsigned long long* stage = (unsigned long long*)agghR;   // NE * 8B
    __half*  aggh    = (__half*)agghR;             // NN*64 half (12.8 MB)
    // h2R aliases: aggx (gather1..mm1s), srcs (csr..gather2), h1h2 (bn_apply1h..gather2); then h2 fp16 (mm2m..bn_pool2)
    float*   aggx    = h2R;                        // NN*16 floats
    int*     srcs    = (int*)(h2R + NN * 16);      // NE ints
    __half2* h1h2    = (__half2*)(h2R + NN * 16 + NE);  // NN*32 half2
    __half*  h2      = (__half*)h2R;               // NN*128 half (25.6 MB)

    // ---- CSR build ----
    k_init<<<1, 1024, 0, stream>>>(bcnt, sums1, sums2);
    k_bcnt<<<(NE + 8191) / 8192, 256, 0, stream>>>(dst, bcnt);
    k_bscan<<<1, 512, 0, stream>>>(bcnt, bbase, bcur);
    k_bucket<<<(NE + 8191) / 8192, 256, 0, stream>>>(src, dst, bcur, stage);
    k_csr<<<NB, 256, 0, stream>>>(stage, bbase, x, deg_i, row_start, dinv, srcs, xh2);

    // ---- layer 1 ----
    k_gather1<<<(NN + 3) / 4, 256, 0, stream>>>((const float4*)xh2, srcs, row_start, deg_i, dinv, (float4*)aggx);
    k_mm1s<<<512, 256, 0, stream>>>(aggx, W1, b1, h1h, sums1);
    k_bn_apply1h<<<(NN * 8 + 255) / 256, 256, 0, stream>>>((const float4*)h1h, sums1, g1, be1, dinv, (float4*)h1h2);

    // ---- layer 2 ----
    k_gather2<<<(NN + 3) / 4, 256, 0, stream>>>((const float4*)h1h2, srcs, row_start, deg_i, dinv, (float4*)aggh);
    k_mm2m<<<128, 256, 0, stream>>>(aggh, W2, b2, h2, sums2, pooled);

    // ---- fused BN2+ReLU+pool, then MLP head ----
    k_bn_pool2<<<(NN + 127) / 128, 128, 0, stream>>>(h2, sums2, g2, be2, batch, pooled, cntf);
    k_mlp<<<NG, 64, 0, stream>>>(pooled, cntf, fW1, fb1, fW2, fb2, out);
}